// Round 10
// baseline (448.790 us; speedup 1.0000x reference)
//
#include <hip/hip_runtime.h>
#include <hip/hip_bf16.h>

#define NN 100000
#define NE 1600000
#define NG 512
#define CH3 65536      // keys per chunk (u8-packed counters: 16384 u32 = 64KB LDS)
#define CHW 16384      // u32 words per chunk
#define NCH 2          // ceil(100000/65536)
#define BPC 128        // blocks per chunk
#define ES 12500       // NE / BPC

// Global feature-column permutation: memory position p holds logical column
// perm(p) = (p&7)*16 + (p>>3) — matches MFMA C/D lane layout so GEMM epilogues
// store coalesced.  Applied to Cb/hbf (data), Bf1 k-side, bn_apply/fc1 maps.
// LDS tiles (rootL/aggL) use XOR swizzle: unit = C*16 + (L^C) to kill the
// 16-way write conflicts measured in round 9 (7.0M SQ_LDS_BANK_CONFLICT).

typedef __attribute__((ext_vector_type(8))) short short8;
typedef __attribute__((ext_vector_type(4))) float float4v;

// ---------------------------------------------------------------- utilities

__device__ inline int lower_bound_dev(const int* __restrict__ a, int n, int v) {
    int lo = 0, hi = n;
    while (lo < hi) { int mid = (lo + hi) >> 1; if (a[mid] < v) lo = mid + 1; else hi = mid; }
    return lo;
}

__device__ inline unsigned short f2bf(float x) {
    unsigned u = __float_as_uint(x);
    unsigned r = (u + 0x7fffu + ((u >> 16) & 1u)) >> 16;   // RNE
    return (unsigned short)r;
}

__device__ inline float bf2f(unsigned short h) {
    return __uint_as_float((unsigned)h << 16);
}

// ---------------------------------------------------------------- node types

__global__ void node_type_kernel(const float* __restrict__ x, int* __restrict__ idx, int n) {
    int i = blockIdx.x * blockDim.x + threadIdx.x;
    if (i >= n) return;
    const float* row = x + (size_t)i * 13;
    int b = 0;
    #pragma unroll
    for (int t = 0; t < 13; ++t) if (row[t] > 0.5f) { b = t; }
    idx[i] = b;
}

// ---------------------------------------------------------------- CSR build, key = dst (2 passes)

__global__ __launch_bounds__(256) void hist_kernel(const int* __restrict__ dst,
                                                   unsigned* __restrict__ partials) {
    __shared__ unsigned h[CHW];
    const int b = blockIdx.x, c = blockIdx.y;
    const int lo = c * CH3;
    for (int i = threadIdx.x; i < CHW; i += 256) h[i] = 0;
    __syncthreads();
    const int e0 = b * ES;
    const int e1 = (e0 + ES < NE) ? e0 + ES : NE;
    for (int e = e0 + threadIdx.x; e < e1; e += 256) {
        int k = dst[e] - lo;
        if (k >= 0 && k < CH3) atomicAdd(&h[k >> 2], 1u << ((k & 3) << 3));
    }
    __syncthreads();
    unsigned* out = partials + ((size_t)(c * BPC + b)) * CHW;
    for (int i = threadIdx.x; i < CHW; i += 256) out[i] = h[i];
}

__global__ void hist_reduce(unsigned* __restrict__ partials, int* __restrict__ counts) {
    const int c = blockIdx.y;
    const int i = blockIdx.x * 256 + threadIdx.x;   // [0, CHW)
    size_t base = (size_t)c * BPC * CHW + i;
    unsigned r0 = 0, r1 = 0, r2 = 0, r3 = 0;
    #pragma unroll 4
    for (int b = 0; b < BPC; ++b) {
        unsigned t = partials[base + (size_t)b * CHW];
        partials[base + (size_t)b * CHW] = r0 | (r1 << 8) | (r2 << 16) | (r3 << 24);
        r0 += t & 0xffu; r1 += (t >> 8) & 0xffu; r2 += (t >> 16) & 0xffu; r3 += t >> 24;
    }
    int k0 = c * CH3 + 4 * i;
    if (k0 < NN)     counts[k0]     = (int)r0;
    if (k0 + 1 < NN) counts[k0 + 1] = (int)r1;
    if (k0 + 2 < NN) counts[k0 + 2] = (int)r2;
    if (k0 + 3 < NN) counts[k0 + 3] = (int)r3;
}

__global__ __launch_bounds__(256) void scan1(const int* __restrict__ counts, int* __restrict__ offs,
                                             int* __restrict__ bsums, int n) {
    __shared__ int wsum[4];
    const int base = blockIdx.x * 1024 + threadIdx.x * 4;
    int v[4]; int loc = 0;
    #pragma unroll
    for (int j = 0; j < 4; ++j) { int idx = base + j; v[j] = (idx < n) ? counts[idx] : 0; loc += v[j]; }
    const int lane = threadIdx.x & 63, wid = threadIdx.x >> 6;
    int sc = loc;
    #pragma unroll
    for (int o = 1; o < 64; o <<= 1) { int t = __shfl_up(sc, o, 64); if (lane >= o) sc += t; }
    if (lane == 63) wsum[wid] = sc;
    __syncthreads();
    int wbase = 0;
    for (int w = 0; w < wid; ++w) wbase += wsum[w];
    int run = wbase + sc - loc;
    #pragma unroll
    for (int j = 0; j < 4; ++j) { int idx = base + j; if (idx < n) offs[idx] = run; run += v[j]; }
    if (threadIdx.x == 255) bsums[blockIdx.x] = wbase + sc;
}

__global__ void scan2(int* __restrict__ bsums, int* __restrict__ offs, int nb, int n) {
    const int lane = threadIdx.x;   // 64 threads
    int carry = 0;
    for (int base = 0; base < nb; base += 64) {
        int idx = base + lane;
        int v = (idx < nb) ? bsums[idx] : 0;
        int sc = v;
        #pragma unroll
        for (int o = 1; o < 64; o <<= 1) { int t = __shfl_up(sc, o, 64); if (lane >= o) sc += t; }
        if (idx < nb) bsums[idx] = carry + sc - v;
        int tot = __shfl(sc, 63, 64);
        carry += tot;
    }
    if (lane == 0) offs[n] = carry;
}

__global__ __launch_bounds__(256) void scan3(int* __restrict__ offs, const int* __restrict__ bsums, int n) {
    const int s = bsums[blockIdx.x];
    const int base = blockIdx.x * 1024 + threadIdx.x * 4;
    #pragma unroll
    for (int j = 0; j < 4; ++j) { int idx = base + j; if (idx < n) offs[idx] += s; }
}

// placement: LDS u8 cursors; payload = src | (rel<<17)   (src < 2^17)
__global__ __launch_bounds__(256) void place_kernel(const int* __restrict__ dst,
                                                    const int* __restrict__ et,
                                                    const int* __restrict__ src,
                                                    const int* __restrict__ offs,
                                                    const unsigned* __restrict__ partials,
                                                    int* __restrict__ sortedSrc) {
    __shared__ unsigned cur[CHW];
    const int b = blockIdx.x, c = blockIdx.y;
    const int lo = c * CH3;
    const unsigned* pb = partials + ((size_t)(c * BPC + b)) * CHW;
    for (int i = threadIdx.x; i < CHW; i += 256) cur[i] = pb[i];
    __syncthreads();
    const int e0 = b * ES;
    const int e1 = (e0 + ES < NE) ? e0 + ES : NE;
    for (int e = e0 + threadIdx.x; e < e1; e += 256) {
        int key = dst[e];
        int k = key - lo;
        if (k >= 0 && k < CH3) {
            int sh = (k & 3) << 3;
            unsigned old = atomicAdd(&cur[k >> 2], 1u << sh);
            int my = (int)((old >> sh) & 0xffu);
            int pos = offs[key] + my;
            sortedSrc[pos] = src[e] | (et[e] << 17);
        }
    }
}

// ---------------------------------------------------------------- rel-sort segments + layer-0 A matrix
// One thread per node: split its CSR segment into 4 relation runs (sorted2, offs4;
// payload becomes bare src) and build the layer-0 type-histogram A0 fragments.
// offs4[4n+r] = start of rel-r run; offs4[4n+4] = next node's start (contiguous).

__global__ __launch_bounds__(256) void relsort_hist(const int* __restrict__ sortedSrc,
                                                    const int* __restrict__ offs,
                                                    const int* __restrict__ ntype,
                                                    int* __restrict__ sorted2,
                                                    int* __restrict__ offs4,
                                                    unsigned short* __restrict__ A0) {
    __shared__ unsigned cnt[256][13];
    const int tid = threadIdx.x;
    const int n = blockIdx.x * 256 + tid;
    if (n >= NN) return;
    #pragma unroll
    for (int t = 0; t < 13; ++t) cnt[tid][t] = 0;
    const int o0 = offs[n], o1 = offs[n + 1];
    unsigned relc = 0;                                 // 4 u8 rel counts
    for (int i = o0; i < o1; ++i) {
        int v = sortedSrc[i];
        int s = v & 0x1ffff, r = v >> 17;
        cnt[tid][ntype[s]] += 1u << (r << 3);
        relc += 1u << (r << 3);
    }
    int b0 = o0;
    int b1 = b0 + (int)(relc & 0xffu);
    int b2 = b1 + (int)((relc >> 8) & 0xffu);
    int b3 = b2 + (int)((relc >> 16) & 0xffu);
    offs4[n * 4 + 0] = b0; offs4[n * 4 + 1] = b1;
    offs4[n * 4 + 2] = b2; offs4[n * 4 + 3] = b3;
    if (n == NN - 1) offs4[4 * NN] = o1;
    int c0 = b0, c1 = b1, c2 = b2, c3 = b3;
    for (int i = o0; i < o1; ++i) {
        int v = sortedSrc[i];
        int s = v & 0x1ffff, r = v >> 17;
        int pos;
        if (r == 0) pos = c0++;
        else if (r == 1) pos = c1++;
        else if (r == 2) pos = c2++;
        else pos = c3++;
        sorted2[pos] = s;
    }
    // A0 fragments (layer-0): onehot + per-rel type histograms / cnt
    float inv[4];
    #pragma unroll
    for (int r = 0; r < 4; ++r) {
        unsigned c = (relc >> (r << 3)) & 0xffu;
        inv[r] = 1.0f / (float)(c > 0 ? c : 1);
    }
    const int myty = ntype[n];
    const int tile = n >> 4, l16 = n & 15;
    unsigned short* base = A0 + (size_t)tile * 1536 + l16 * 8;
    #pragma unroll
    for (int ks = 0; ks < 3; ++ks) {
        #pragma unroll
        for (int quad = 0; quad < 4; ++quad) {
            unsigned short vals[8];
            #pragma unroll
            for (int j = 0; j < 8; ++j) {
                int p = ks * 32 + quad * 8 + j;
                float v;
                if (p < 32) v = (p == myty) ? 1.0f : 0.0f;
                else {
                    int r = (p - 32) >> 4, tt = (p - 32) & 15;
                    v = (tt < 13) ? (float)((cnt[tid][tt] >> (r << 3)) & 0xffu) * inv[r] : 0.0f;
                }
                vals[j] = f2bf(v);
            }
            *(uint4*)(base + ks * 512 + quad * 128) = *(uint4*)vals;
        }
    }
}

// ---------------------------------------------------------------- layer-0 B: B0 = emb @ [Wroot0; Wrel0_r]
// Zeroes all 8 bnSums copies (blocks 0..7).

__global__ void build_B0(const float* __restrict__ emb, const float* __restrict__ Wroot,
                         const float* __restrict__ Wrel, unsigned short* __restrict__ B0f,
                         float* __restrict__ bnSums) {
    if (blockIdx.x < 8) bnSums[blockIdx.x * 256 + threadIdx.x] = 0.f;
    int i = blockIdx.x * 256 + threadIdx.x;   // 3*8*64*8 = 12288
    if (i >= 12288) return;
    int j = i & 7;
    int lane = (i >> 3) & 63;
    int t = (i >> 9) & 7;
    int ks = i >> 12;
    int n = t * 16 + (lane & 15);
    int p = ks * 32 + (lane >> 4) * 8 + j;
    float val = 0.f;
    if (p < 32) {
        if (p < 13) {
            const float* er = emb + (size_t)p * 128;
            const float* wc = Wroot + n;
            float acc = 0.f;
            for (int k = 0; k < 128; ++k) acc += er[k] * wc[(size_t)k * 128];
            val = acc;
        }
    } else {
        int r = (p - 32) >> 4, tt = (p - 32) & 15;
        if (tt < 13) {
            const float* er = emb + (size_t)tt * 128;
            const float* wc = Wrel + ((size_t)r * 128) * 128 + n;
            float acc = 0.f;
            for (int k = 0; k < 128; ++k) acc += er[k] * wc[(size_t)k * 128];
            val = acc;
        }
    }
    B0f[i] = f2bf(val);
}

// ---------------------------------------------------------------- layer-1 B fragments (k-side permuted)
// Zeroes all 8 bnSums copies (blocks 0..7).

__global__ void build_Bf1(const float* __restrict__ Wroot, const float* __restrict__ Wrel,
                          unsigned short* __restrict__ Bf, float* __restrict__ bnSums) {
    if (blockIdx.x < 8) bnSums[blockIdx.x * 256 + threadIdx.x] = 0.f;
    int i = blockIdx.x * 256 + threadIdx.x;   // 5*4*8*64*8 = 81920
    if (i >= 81920) return;
    int j = i & 7;
    int lane = (i >> 3) & 63;
    int t = (i >> 9) & 7;
    int ks = (i >> 12) & 3;
    int kc = i >> 14;
    int n = t * 16 + (lane & 15);
    int kcol = j * 16 + ks * 4 + (lane >> 4);    // permuted logical k
    float w;
    if (kc == 0) w = Wroot[16384 + (size_t)kcol * 128 + n];
    else {
        int r = kc - 1;
        w = Wrel[(((size_t)(4 + r) * 128) + kcol) * 128 + n];
    }
    Bf[i] = f2bf(w);
}

// ---------------------------------------------------------------- layer-0 GEMM (K=96)

__global__ __launch_bounds__(256) void gemm0_mfma(const unsigned short* __restrict__ A0,
                                                  const unsigned short* __restrict__ B0f,
                                                  const float* __restrict__ bias,
                                                  unsigned short* __restrict__ Cb,
                                                  float* __restrict__ bnSums, int M) {
    __shared__ float sred[2][4][128];
    const int tid = threadIdx.x;
    const int wv = tid >> 6, lane = tid & 63;
    const int l16 = lane & 15, quad = lane >> 4;
    const int rowbase = blockIdx.x * 128 + wv * 32;
    const int tmax = (M >> 4) - 1;
    int tile0 = blockIdx.x * 8 + wv * 2; if (tile0 > tmax) tile0 = tmax;
    int tile1 = tile0 + 1;               if (tile1 > tmax) tile1 = tmax;

    float4v acc[2][8];
    #pragma unroll
    for (int t = 0; t < 8; ++t) {
        float bv = bias[t * 16 + l16];
        float4v av = {bv, bv, bv, bv};
        acc[0][t] = av; acc[1][t] = av;
    }

    const unsigned short* bl = B0f + lane * 8;
    const unsigned short* F0 = A0 + (size_t)tile0 * 1536 + quad * 128 + l16 * 8;
    const unsigned short* F1 = A0 + (size_t)tile1 * 1536 + quad * 128 + l16 * 8;
    #pragma unroll
    for (int ks = 0; ks < 3; ++ks) {
        short8 af0 = *(const short8*)(F0 + ks * 512);
        short8 af1 = *(const short8*)(F1 + ks * 512);
        const unsigned short* bp = bl + ((ks * 8) << 9);
        #pragma unroll
        for (int t = 0; t < 8; ++t) {
            short8 bf = *(const short8*)(bp + (t << 9));
            acc[0][t] = __builtin_amdgcn_mfma_f32_16x16x32_bf16(af0, bf, acc[0][t], 0, 0, 0);
            acc[1][t] = __builtin_amdgcn_mfma_f32_16x16x32_bf16(af1, bf, acc[1][t], 0, 0, 0);
        }
    }

    #pragma unroll
    for (int h = 0; h < 2; ++h) {
        #pragma unroll
        for (int rg = 0; rg < 4; ++rg) {
            int rr = rowbase + h * 16 + quad * 4 + rg;
            if (rr < M) {
                unsigned short v[8];
                #pragma unroll
                for (int t = 0; t < 8; ++t) v[t] = f2bf(acc[h][t][rg]);
                *(uint4*)(Cb + (size_t)rr * 128 + l16 * 8) = *(uint4*)v;
            }
        }
    }
    float s[8], q[8];
    #pragma unroll
    for (int t = 0; t < 8; ++t) {
        s[t] = 0.f; q[t] = 0.f;
        #pragma unroll
        for (int h = 0; h < 2; ++h) {
            #pragma unroll
            for (int rg = 0; rg < 4; ++rg) {
                int rr = rowbase + h * 16 + quad * 4 + rg;
                if (rr < M) { float v = acc[h][t][rg]; s[t] += v; q[t] += v * v; }
            }
        }
    }
    #pragma unroll
    for (int t = 0; t < 8; ++t) {
        s[t] += __shfl_down(s[t], 32, 64); q[t] += __shfl_down(q[t], 32, 64);
        s[t] += __shfl_down(s[t], 16, 64); q[t] += __shfl_down(q[t], 16, 64);
    }
    if (lane < 16) {
        #pragma unroll
        for (int t = 0; t < 8; ++t) {
            sred[0][wv][t * 16 + l16] = s[t];
            sred[1][wv][t * 16 + l16] = q[t];
        }
    }
    __syncthreads();
    if (tid < 128) {
        float S = sred[0][0][tid] + sred[0][1][tid] + sred[0][2][tid] + sred[0][3][tid];
        float Q = sred[1][0][tid] + sred[1][1][tid] + sred[1][2][tid] + sred[1][3][tid];
        float* bnS = bnSums + ((blockIdx.x & 7) << 8);
        unsafeAtomicAdd(bnS + tid, S);
        unsafeAtomicAdd(bnS + 128 + tid, Q);
    }
}

// ---------------------------------------------------------------- FUSED layer-1: gather + GEMM
// Rel-sorted segments -> single-accumulator gather (16 VALU/edge-lane vs 44).
// LDS tiles XOR-swizzled (unit = C*16 + (L^C)) -> conflict-free writes & reads.

__global__ __launch_bounds__(256) void gather_gemm1(const unsigned short* __restrict__ hbf,
                                                    const int* __restrict__ sorted2,
                                                    const int* __restrict__ offs4,
                                                    const unsigned short* __restrict__ Bf,
                                                    const float* __restrict__ bias,
                                                    unsigned short* __restrict__ Cb,
                                                    float* __restrict__ bnSums) {
    __shared__ unsigned short rootL[2048];   // 4KB  (16B-unit swizzled)
    __shared__ unsigned short aggL[8192];    // 16KB (4 rel blocks, swizzled)
    const int tid = threadIdx.x;
    const int tile = blockIdx.x;
    {
        const int l16g = tid >> 4;
        const int cidx = tid & 15;
        const int c8 = cidx << 3;
        const int n = tile * 16 + l16g;                  // NN = 6250*16 exact
        const int pu = cidx * 16 + (l16g ^ cidx);        // swizzled unit
        uint4 ru = *(const uint4*)(hbf + (size_t)n * 128 + c8);
        *(uint4*)(rootL + pu * 8) = ru;

        const int ob = n * 4;
        #pragma unroll
        for (int r = 0; r < 4; ++r) {
            const int i0 = offs4[ob + r];
            const int i1 = offs4[ob + r + 1];
            float aA[8], aB[8];
            #pragma unroll
            for (int j = 0; j < 8; ++j) { aA[j] = 0.f; aB[j] = 0.f; }
            int i = i0;
            for (; i + 2 <= i1; i += 2) {
                int s0 = sorted2[i], s1 = sorted2[i + 1];
                uint4 u0 = *(const uint4*)(hbf + (size_t)s0 * 128 + c8);
                uint4 u1 = *(const uint4*)(hbf + (size_t)s1 * 128 + c8);
                aA[0] += __uint_as_float(u0.x << 16); aA[1] += __uint_as_float(u0.x & 0xffff0000u);
                aA[2] += __uint_as_float(u0.y << 16); aA[3] += __uint_as_float(u0.y & 0xffff0000u);
                aA[4] += __uint_as_float(u0.z << 16); aA[5] += __uint_as_float(u0.z & 0xffff0000u);
                aA[6] += __uint_as_float(u0.w << 16); aA[7] += __uint_as_float(u0.w & 0xffff0000u);
                aB[0] += __uint_as_float(u1.x << 16); aB[1] += __uint_as_float(u1.x & 0xffff0000u);
                aB[2] += __uint_as_float(u1.y << 16); aB[3] += __uint_as_float(u1.y & 0xffff0000u);
                aB[4] += __uint_as_float(u1.z << 16); aB[5] += __uint_as_float(u1.z & 0xffff0000u);
                aB[6] += __uint_as_float(u1.w << 16); aB[7] += __uint_as_float(u1.w & 0xffff0000u);
            }
            if (i < i1) {
                int s0 = sorted2[i];
                uint4 u0 = *(const uint4*)(hbf + (size_t)s0 * 128 + c8);
                aA[0] += __uint_as_float(u0.x << 16); aA[1] += __uint_as_float(u0.x & 0xffff0000u);
                aA[2] += __uint_as_float(u0.y << 16); aA[3] += __uint_as_float(u0.y & 0xffff0000u);
                aA[4] += __uint_as_float(u0.z << 16); aA[5] += __uint_as_float(u0.z & 0xffff0000u);
                aA[6] += __uint_as_float(u0.w << 16); aA[7] += __uint_as_float(u0.w & 0xffff0000u);
            }
            const int cnt = i1 - i0;
            const float inv = 1.0f / (float)(cnt > 0 ? cnt : 1);
            unsigned short v[8];
            #pragma unroll
            for (int j = 0; j < 8; ++j) v[j] = f2bf((aA[j] + aB[j]) * inv);
            *(uint4*)(aggL + r * 2048 + pu * 8) = *(uint4*)v;
        }
    }
    __syncthreads();

    // ---- GEMM phase: wave wv handles output cols t0=2wv, t0+1
    const int wv = tid >> 6, lane = tid & 63;
    const int l16 = lane & 15, quad = lane >> 4;
    const int t0 = wv << 1;
    float4v acc0, acc1;
    {
        float b0v = bias[t0 * 16 + l16];
        float b1v = bias[(t0 + 1) * 16 + l16];
        float4v a0v = {b0v, b0v, b0v, b0v};
        float4v a1v = {b1v, b1v, b1v, b1v};
        acc0 = a0v; acc1 = a1v;
    }
    const unsigned short* bl = Bf + lane * 8;
    #pragma unroll
    for (int kc = 0; kc < 5; ++kc) {
        const unsigned short* Abase = (kc == 0) ? rootL : (aggL + (kc - 1) * 2048);
        #pragma unroll
        for (int ks = 0; ks < 4; ++ks) {
            const int C = ks * 4 + quad;
            const int p = C * 16 + (l16 ^ C);            // swizzled unit
            short8 af = *(const short8*)(Abase + p * 8);
            const unsigned short* bp = bl + (((kc * 4 + ks) * 8 + t0) << 9);
            short8 b0 = *(const short8*)(bp);
            short8 b1 = *(const short8*)(bp + 512);
            acc0 = __builtin_amdgcn_mfma_f32_16x16x32_bf16(af, b0, acc0, 0, 0, 0);
            acc1 = __builtin_amdgcn_mfma_f32_16x16x32_bf16(af, b1, acc1, 0, 0, 0);
        }
    }
    // store: row = tile*16 + quad*4+rg; mem pos l16*8 + t0 (+1) — one dword/lane/rg
    const int rowbase = tile * 16;
    #pragma unroll
    for (int rg = 0; rg < 4; ++rg) {
        int rr = rowbase + quad * 4 + rg;
        unsigned pk = (unsigned)f2bf(acc0[rg]) | ((unsigned)f2bf(acc1[rg]) << 16);
        *(unsigned*)(Cb + (size_t)rr * 128 + l16 * 8 + t0) = pk;
    }
    // BN stats: this wave owns logical cols t0*16+l16 and (t0+1)*16+l16
    float s0 = 0.f, q0 = 0.f, s1 = 0.f, q1 = 0.f;
    #pragma unroll
    for (int rg = 0; rg < 4; ++rg) {
        float v0 = acc0[rg], v1 = acc1[rg];
        s0 += v0; q0 += v0 * v0; s1 += v1; q1 += v1 * v1;
    }
    s0 += __shfl_down(s0, 32, 64); q0 += __shfl_down(q0, 32, 64);
    s1 += __shfl_down(s1, 32, 64); q1 += __shfl_down(q1, 32, 64);
    s0 += __shfl_down(s0, 16, 64); q0 += __shfl_down(q0, 16, 64);
    s1 += __shfl_down(s1, 16, 64); q1 += __shfl_down(q1, 16, 64);
    if (lane < 16) {
        float* bnS = bnSums + ((tile & 7) << 8);
        unsafeAtomicAdd(bnS + t0 * 16 + l16, s0);
        unsafeAtomicAdd(bnS + 128 + t0 * 16 + l16, q0);
        unsafeAtomicAdd(bnS + (t0 + 1) * 16 + l16, s1);
        unsafeAtomicAdd(bnS + 128 + (t0 + 1) * 16 + l16, q1);
    }
}

// ---------------------------------------------------------------- BN finalize: fold 8 copies -> mu, rsig

__global__ void bn_finalize(const float* __restrict__ bnSums, float* __restrict__ fin, int n) {
    const int c = threadIdx.x;   // 128
    float s = 0.f, q = 0.f;
    #pragma unroll
    for (int j = 0; j < 8; ++j) { s += bnSums[j * 256 + c]; q += bnSums[j * 256 + 128 + c]; }
    const float invn = 1.0f / (float)n;
    float mu = s * invn;
    float var = q * invn - mu * mu; if (var < 0.f) var = 0.f;
    fin[c] = mu;
    fin[128 + c] = rsqrtf(var + 1e-5f);
}

// ---------------------------------------------------------------- fused BN/PReLU/L2norm (permuted cols)

__global__ __launch_bounds__(256) void bn_apply_kernel(const unsigned short* __restrict__ Cb,
                                unsigned short* __restrict__ hbf,
                                const float* __restrict__ fin,
                                const float* __restrict__ gamma, const float* __restrict__ beta,
                                const float* __restrict__ prelu_a, int layer) {
    const int tid = threadIdx.x;
    const int row = blockIdx.x * 16 + (tid >> 4);
    const int li = tid & 15;
    const int p8 = li << 3;
    const float a = prelu_a[layer];
    uint4 u = *(const uint4*)(Cb + (size_t)row * 128 + p8);
    float v[8];
    v[0] = __uint_as_float(u.x << 16); v[1] = __uint_as_float(u.x & 0xffff0000u);
    v[2] = __uint_as_float(u.y << 16); v[3] = __uint_as_float(u.y & 0xffff0000u);
    v[4] = __uint_as_float(u.z << 16); v[5] = __uint_as_float(u.z & 0xffff0000u);
    v[6] = __uint_as_float(u.w << 16); v[7] = __uint_as_float(u.w & 0xffff0000u);
    float t[8]; float ss = 0.f;
    #pragma unroll
    for (int j = 0; j < 8; ++j) {
        int cc = j * 16 + li;                      // logical column
        float tv = (v[j] - fin[cc]) * fin[128 + cc] * gamma[cc] + beta[cc];
        tv = (tv >= 0.f) ? tv : a * tv;
        t[j] = tv; ss += tv * tv;
    }
    ss += __shfl_xor(ss, 1, 64);
    ss += __shfl_xor(ss, 2, 64);
    ss += __shfl_xor(ss, 4, 64);
    ss += __shfl_xor(ss, 8, 64);
    const float scale = 1.0f / fmaxf(sqrtf(ss), 1e-12f);
    unsigned short o[8];
    #pragma unroll
    for (int j = 0; j < 8; ++j) o[j] = f2bf(t[j] * scale);
    *(uint4*)(hbf + (size_t)row * 128 + p8) = *(uint4*)o;
}

// ---------------------------------------------------------------- pooling + MLP

__global__ void pool_kernel(const unsigned short* __restrict__ hbf, const int* __restrict__ batch,
                            float* __restrict__ g, int n) {
    const int gid = blockIdx.x;   // 512 blocks
    const int f = threadIdx.x;    // 128 threads (mem-permuted col)
    const int lo = lower_bound_dev(batch, n, gid);
    const int hi = lower_bound_dev(batch, n, gid + 1);
    float s = 0.f;
    for (int r = lo; r < hi; ++r) s += bf2f(hbf[(size_t)r * 128 + f]);
    int c = hi - lo;
    g[gid * 128 + f] = s / (float)(c > 0 ? c : 1);
}

__global__ void fc1_kernel(const float* __restrict__ g, const float* __restrict__ w,
                           const float* __restrict__ b, float* __restrict__ o) {
    const int row = blockIdx.x;   // 512
    const int j = threadIdx.x;    // 256
    float acc = b[j];
    #pragma unroll 8
    for (int k = 0; k < 128; ++k) {
        int lk = (k & 7) * 16 + (k >> 3);         // logical feature for mem pos k
        acc += g[row * 128 + k] * w[lk * 256 + j];
    }
    o[row * 256 + j] = fmaxf(acc, 0.f);
}

__global__ void fc2_kernel(const float* __restrict__ g, const float* __restrict__ w,
                           const float* __restrict__ b, float* __restrict__ o) {
    const int row = blockIdx.x;   // 512
    const int j = threadIdx.x;    // 128
    float acc = b[j];
    #pragma unroll 8
    for (int k = 0; k < 256; ++k) acc += g[row * 256 + k] * w[k * 128 + j];
    o[row * 128 + j] = fmaxf(acc, 0.f);
}

__global__ void fco_kernel(const float* __restrict__ g, const float* __restrict__ w,
                           const float* __restrict__ b, float* __restrict__ o) {
    const int row = blockIdx.x * blockDim.x + threadIdx.x;
    if (row >= NG) return;
    float acc = b[0];
    #pragma unroll 8
    for (int k = 0; k < 128; ++k) acc += g[row * 128 + k] * w[k];
    o[row] = acc;
}

// ---------------------------------------------------------------- launcher

extern "C" void kernel_launch(void* const* d_in, const int* in_sizes, int n_in,
                              void* d_out, int out_size, void* d_ws, size_t ws_size,
                              hipStream_t stream) {
    const float* x      = (const float*)d_in[0];
    const int*   eidx   = (const int*)d_in[1];
    const int*   etype  = (const int*)d_in[2];
    const int*   batch  = (const int*)d_in[3];
    const float* emb    = (const float*)d_in[4];
    const float* Wrel   = (const float*)d_in[5];
    const float* Wroot  = (const float*)d_in[6];
    const float* cbias  = (const float*)d_in[7];
    const float* gamma  = (const float*)d_in[8];
    const float* beta   = (const float*)d_in[9];
    const float* prelua = (const float*)d_in[10];
    const float* fc1w   = (const float*)d_in[11];
    const float* fc1b   = (const float*)d_in[12];
    const float* fc2w   = (const float*)d_in[13];
    const float* fc2b   = (const float*)d_in[14];
    const float* outw   = (const float*)d_in[15];
    const float* outb   = (const float*)d_in[16];
    float* out = (float*)d_out;

    const int* src = eidx;
    const int* dst = eidx + NE;

    // workspace carve-up (aligned 256B)
    char* p = (char*)d_ws;
    auto alloc = [&](size_t bytes) { char* r = p; p += (bytes + 255) & ~(size_t)255; return r; };
    unsigned short* hbf   = (unsigned short*)alloc((size_t)NN * 128 * 2);  // 25.6 MB
    unsigned short* Cb    = (unsigned short*)alloc((size_t)NN * 128 * 2);  // 25.6 MB
    char*  scratch   = (char*)alloc((size_t)24 << 20);                     // partials / A0 (sequential)
    int*   sortedSrc = (int*)alloc((size_t)NE * 4);                        // 6.4 MB
    int*   sorted2   = (int*)alloc((size_t)NE * 4);                        // 6.4 MB (rel-sorted)
    int*   offs      = (int*)alloc((size_t)(NN + 1) * 4);
    int*   offs4     = (int*)alloc((size_t)(4 * NN + 1) * 4);              // 1.6 MB
    int*   bsums     = (int*)alloc(1024);
    int*   ntype     = (int*)alloc((size_t)NN * 4);
    unsigned short* Bf1 = (unsigned short*)alloc((size_t)81920 * 2);
    unsigned short* B0f = (unsigned short*)alloc((size_t)12288 * 2);
    float* bnSums  = (float*)alloc(2048 * 4);
    float* bnFin   = (float*)alloc(256 * 4);
    float* g0      = (float*)alloc((size_t)NG * 128 * 4);
    float* g1      = (float*)alloc((size_t)NG * 256 * 4);
    float* g2      = (float*)alloc((size_t)NG * 128 * 4);

    unsigned* partials = (unsigned*)scratch;          // 16.8 MB, dead after place
    unsigned short* A0 = (unsigned short*)scratch;    // 19.2 MB, built after place

    const int NBLK = (NN + 1023) / 1024;   // 98

    // ---- node types
    node_type_kernel<<<(NN + 255) / 256, 256, 0, stream>>>(x, ntype, NN);

    // ---- CSR build over dst (2 chunk passes, u8 counters, no global atomics)
    hist_kernel<<<dim3(BPC, NCH), 256, 0, stream>>>(dst, partials);
    hist_reduce<<<dim3(CHW / 256, NCH), 256, 0, stream>>>(partials, offs);
    scan1<<<NBLK, 256, 0, stream>>>(offs, offs, bsums, NN);
    scan2<<<1, 64, 0, stream>>>(bsums, offs, NBLK, NN);
    scan3<<<NBLK, 256, 0, stream>>>(offs, bsums, NN);
    place_kernel<<<dim3(BPC, NCH), 256, 0, stream>>>(dst, etype, src, offs, partials, sortedSrc);

    // ---- rel-sort segments + layer-0 A0 build (replaces hist_A0)
    relsort_hist<<<(NN + 255) / 256, 256, 0, stream>>>(sortedSrc, offs, ntype,
                                                       sorted2, offs4, A0);

    // ---- layer 0: type-histogram GEMM
    build_B0<<<48, 256, 0, stream>>>(emb, Wroot, Wrel, B0f, bnSums);
    gemm0_mfma<<<(NN + 127) / 128, 256, 0, stream>>>(A0, B0f, cbias, Cb, bnSums, NN);
    bn_finalize<<<1, 128, 0, stream>>>(bnSums, bnFin, NN);
    bn_apply_kernel<<<NN / 16, 256, 0, stream>>>(Cb, hbf, bnFin, gamma, beta, prelua, 0);

    // ---- layer 1: fused gather + GEMM (rel-sorted, swizzled LDS)
    build_Bf1<<<320, 256, 0, stream>>>(Wroot, Wrel, Bf1, bnSums);
    gather_gemm1<<<NN / 16, 256, 0, stream>>>(hbf, sorted2, offs4, Bf1, cbias + 128, Cb, bnSums);
    bn_finalize<<<1, 128, 0, stream>>>(bnSums, bnFin, NN);
    bn_apply_kernel<<<NN / 16, 256, 0, stream>>>(Cb, hbf, bnFin, gamma + 128, beta + 128, prelua, 1);

    // ---- pool + MLP
    pool_kernel<<<NG, 128, 0, stream>>>(hbf, batch, g0, NN);
    fc1_kernel<<<NG, 256, 0, stream>>>(g0, fc1w, fc1b, g1);
    fc2_kernel<<<NG, 128, 0, stream>>>(g1, fc2w, fc2b, g2);
    fco_kernel<<<2, 256, 0, stream>>>(g2, outw, outb, out);
}

// Round 11
// 380.777 us; speedup vs baseline: 1.1786x; 1.1786x over previous
//
#include <hip/hip_runtime.h>
#include <hip/hip_bf16.h>

#define NN 100000
#define NE 1600000
#define NG 512
#define CH3 65536      // keys per chunk (u8-packed counters: 16384 u32 = 64KB LDS)
#define CHW 16384      // u32 words per chunk
#define NCH 2          // ceil(100000/65536)
#define BPC 128        // blocks per chunk
#define ES 12500       // NE / BPC

// Feature-column permutation: mem position p holds logical col (p&7)*16+(p>>3).
// sortedSrc payload: src[0:17) | type[17:21) | rel[21:23).  sorted2 = bare src.
// LDS tiles XOR-swizzled: unit = C*16 + (L^C).

typedef __attribute__((ext_vector_type(8))) short short8;
typedef __attribute__((ext_vector_type(4))) float float4v;

// ---------------------------------------------------------------- utilities

__device__ inline int lower_bound_dev(const int* __restrict__ a, int n, int v) {
    int lo = 0, hi = n;
    while (lo < hi) { int mid = (lo + hi) >> 1; if (a[mid] < v) lo = mid + 1; else hi = mid; }
    return lo;
}

__device__ inline unsigned short f2bf(float x) {
    unsigned u = __float_as_uint(x);
    unsigned r = (u + 0x7fffu + ((u >> 16) & 1u)) >> 16;   // RNE
    return (unsigned short)r;
}

__device__ inline float bf2f(unsigned short h) {
    return __uint_as_float((unsigned)h << 16);
}

// ---------------------------------------------------------------- node types + src-type pack

__global__ void node_type_kernel(const float* __restrict__ x, int* __restrict__ idx, int n) {
    int i = blockIdx.x * blockDim.x + threadIdx.x;
    if (i >= n) return;
    const float* row = x + (size_t)i * 13;
    int b = 0;
    #pragma unroll
    for (int t = 0; t < 13; ++t) if (row[t] > 0.5f) { b = t; }
    idx[i] = b;
}

__global__ void pack_src_type(const int* __restrict__ src, const int* __restrict__ ntype,
                              int* __restrict__ srcT) {
    int e = blockIdx.x * 256 + threadIdx.x;
    if (e >= NE) return;
    int s = src[e];
    srcT[e] = s | (ntype[s] << 17);
}

// ---------------------------------------------------------------- CSR build, key = dst (2 passes)

__global__ __launch_bounds__(256) void hist_kernel(const int* __restrict__ dst,
                                                   unsigned* __restrict__ partials) {
    __shared__ unsigned h[CHW];
    const int b = blockIdx.x, c = blockIdx.y;
    const int lo = c * CH3;
    for (int i = threadIdx.x; i < CHW; i += 256) h[i] = 0;
    __syncthreads();
    const int e0 = b * ES;
    const int e1 = (e0 + ES < NE) ? e0 + ES : NE;
    for (int e = e0 + threadIdx.x; e < e1; e += 256) {
        int k = dst[e] - lo;
        if (k >= 0 && k < CH3) atomicAdd(&h[k >> 2], 1u << ((k & 3) << 3));
    }
    __syncthreads();
    unsigned* out = partials + ((size_t)(c * BPC + b)) * CHW;
    for (int i = threadIdx.x; i < CHW; i += 256) out[i] = h[i];
}

__global__ void hist_reduce(unsigned* __restrict__ partials, int* __restrict__ counts) {
    const int c = blockIdx.y;
    const int i = blockIdx.x * 256 + threadIdx.x;   // [0, CHW)
    size_t base = (size_t)c * BPC * CHW + i;
    unsigned r0 = 0, r1 = 0, r2 = 0, r3 = 0;
    #pragma unroll 4
    for (int b = 0; b < BPC; ++b) {
        unsigned t = partials[base + (size_t)b * CHW];
        partials[base + (size_t)b * CHW] = r0 | (r1 << 8) | (r2 << 16) | (r3 << 24);
        r0 += t & 0xffu; r1 += (t >> 8) & 0xffu; r2 += (t >> 16) & 0xffu; r3 += t >> 24;
    }
    int k0 = c * CH3 + 4 * i;
    if (k0 < NN)     counts[k0]     = (int)r0;
    if (k0 + 1 < NN) counts[k0 + 1] = (int)r1;
    if (k0 + 2 < NN) counts[k0 + 2] = (int)r2;
    if (k0 + 3 < NN) counts[k0 + 3] = (int)r3;
}

__global__ __launch_bounds__(256) void scan1(const int* __restrict__ counts, int* __restrict__ offs,
                                             int* __restrict__ bsums, int n) {
    __shared__ int wsum[4];
    const int base = blockIdx.x * 1024 + threadIdx.x * 4;
    int v[4]; int loc = 0;
    #pragma unroll
    for (int j = 0; j < 4; ++j) { int idx = base + j; v[j] = (idx < n) ? counts[idx] : 0; loc += v[j]; }
    const int lane = threadIdx.x & 63, wid = threadIdx.x >> 6;
    int sc = loc;
    #pragma unroll
    for (int o = 1; o < 64; o <<= 1) { int t = __shfl_up(sc, o, 64); if (lane >= o) sc += t; }
    if (lane == 63) wsum[wid] = sc;
    __syncthreads();
    int wbase = 0;
    for (int w = 0; w < wid; ++w) wbase += wsum[w];
    int run = wbase + sc - loc;
    #pragma unroll
    for (int j = 0; j < 4; ++j) { int idx = base + j; if (idx < n) offs[idx] = run; run += v[j]; }
    if (threadIdx.x == 255) bsums[blockIdx.x] = wbase + sc;
}

__global__ void scan2(int* __restrict__ bsums, int* __restrict__ offs, int nb, int n) {
    const int lane = threadIdx.x;   // 64 threads
    int carry = 0;
    for (int base = 0; base < nb; base += 64) {
        int idx = base + lane;
        int v = (idx < nb) ? bsums[idx] : 0;
        int sc = v;
        #pragma unroll
        for (int o = 1; o < 64; o <<= 1) { int t = __shfl_up(sc, o, 64); if (lane >= o) sc += t; }
        if (idx < nb) bsums[idx] = carry + sc - v;
        int tot = __shfl(sc, 63, 64);
        carry += tot;
    }
    if (lane == 0) offs[n] = carry;
}

__global__ __launch_bounds__(256) void scan3(int* __restrict__ offs, const int* __restrict__ bsums, int n) {
    const int s = bsums[blockIdx.x];
    const int base = blockIdx.x * 1024 + threadIdx.x * 4;
    #pragma unroll
    for (int j = 0; j < 4; ++j) { int idx = base + j; if (idx < n) offs[idx] += s; }
}

// placement: LDS u8 cursors; payload = srcT | (rel<<21)
__global__ __launch_bounds__(256) void place_kernel(const int* __restrict__ dst,
                                                    const int* __restrict__ et,
                                                    const int* __restrict__ srcT,
                                                    const int* __restrict__ offs,
                                                    const unsigned* __restrict__ partials,
                                                    int* __restrict__ sortedSrc) {
    __shared__ unsigned cur[CHW];
    const int b = blockIdx.x, c = blockIdx.y;
    const int lo = c * CH3;
    const unsigned* pb = partials + ((size_t)(c * BPC + b)) * CHW;
    for (int i = threadIdx.x; i < CHW; i += 256) cur[i] = pb[i];
    __syncthreads();
    const int e0 = b * ES;
    const int e1 = (e0 + ES < NE) ? e0 + ES : NE;
    for (int e = e0 + threadIdx.x; e < e1; e += 256) {
        int key = dst[e];
        int k = key - lo;
        if (k >= 0 && k < CH3) {
            int sh = (k & 3) << 3;
            unsigned old = atomicAdd(&cur[k >> 2], 1u << sh);
            int my = (int)((old >> sh) & 0xffu);
            int pos = offs[key] + my;
            sortedSrc[pos] = srcT[e] | (et[e] << 21);
        }
    }
}

// ---------------------------------------------------------------- rel-sort segments + layer-0 A matrix
// Type now carried in payload -> no random gathers here.

__global__ __launch_bounds__(256) void relsort_hist(const int* __restrict__ sortedSrc,
                                                    const int* __restrict__ offs,
                                                    const int* __restrict__ ntype,
                                                    int* __restrict__ sorted2,
                                                    int* __restrict__ offs4,
                                                    unsigned short* __restrict__ A0) {
    __shared__ unsigned cnt[256][13];
    const int tid = threadIdx.x;
    const int n = blockIdx.x * 256 + tid;
    if (n >= NN) return;
    #pragma unroll
    for (int t = 0; t < 13; ++t) cnt[tid][t] = 0;
    const int o0 = offs[n], o1 = offs[n + 1];
    unsigned relc = 0;
    for (int i = o0; i < o1; ++i) {
        int v = sortedSrc[i];
        int ty = (v >> 17) & 15, r = v >> 21;
        cnt[tid][ty] += 1u << (r << 3);
        relc += 1u << (r << 3);
    }
    int b0 = o0;
    int b1 = b0 + (int)(relc & 0xffu);
    int b2 = b1 + (int)((relc >> 8) & 0xffu);
    int b3 = b2 + (int)((relc >> 16) & 0xffu);
    offs4[n * 4 + 0] = b0; offs4[n * 4 + 1] = b1;
    offs4[n * 4 + 2] = b2; offs4[n * 4 + 3] = b3;
    if (n == NN - 1) offs4[4 * NN] = o1;
    int c0 = b0, c1 = b1, c2 = b2, c3 = b3;
    for (int i = o0; i < o1; ++i) {
        int v = sortedSrc[i];
        int r = v >> 21;
        int pos;
        if (r == 0) pos = c0++;
        else if (r == 1) pos = c1++;
        else if (r == 2) pos = c2++;
        else pos = c3++;
        sorted2[pos] = v & 0x1ffff;
    }
    float inv[4];
    #pragma unroll
    for (int r = 0; r < 4; ++r) {
        unsigned c = (relc >> (r << 3)) & 0xffu;
        inv[r] = 1.0f / (float)(c > 0 ? c : 1);
    }
    const int myty = ntype[n];
    const int tile = n >> 4, l16 = n & 15;
    unsigned short* base = A0 + (size_t)tile * 1536 + l16 * 8;
    #pragma unroll
    for (int ks = 0; ks < 3; ++ks) {
        #pragma unroll
        for (int quad = 0; quad < 4; ++quad) {
            unsigned short vals[8];
            #pragma unroll
            for (int j = 0; j < 8; ++j) {
                int p = ks * 32 + quad * 8 + j;
                float v;
                if (p < 32) v = (p == myty) ? 1.0f : 0.0f;
                else {
                    int r = (p - 32) >> 4, tt = (p - 32) & 15;
                    v = (tt < 13) ? (float)((cnt[tid][tt] >> (r << 3)) & 0xffu) * inv[r] : 0.0f;
                }
                vals[j] = f2bf(v);
            }
            *(uint4*)(base + ks * 512 + quad * 128) = *(uint4*)vals;
        }
    }
}

// ---------------------------------------------------------------- layer-0 B: B0 = emb @ [Wroot0; Wrel0_r]

__global__ void build_B0(const float* __restrict__ emb, const float* __restrict__ Wroot,
                         const float* __restrict__ Wrel, unsigned short* __restrict__ B0f,
                         float* __restrict__ bnSums) {
    if (blockIdx.x < 8) bnSums[blockIdx.x * 256 + threadIdx.x] = 0.f;
    int i = blockIdx.x * 256 + threadIdx.x;   // 3*8*64*8 = 12288
    if (i >= 12288) return;
    int j = i & 7;
    int lane = (i >> 3) & 63;
    int t = (i >> 9) & 7;
    int ks = i >> 12;
    int n = t * 16 + (lane & 15);
    int p = ks * 32 + (lane >> 4) * 8 + j;
    float val = 0.f;
    if (p < 32) {
        if (p < 13) {
            const float* er = emb + (size_t)p * 128;
            const float* wc = Wroot + n;
            float acc = 0.f;
            for (int k = 0; k < 128; ++k) acc += er[k] * wc[(size_t)k * 128];
            val = acc;
        }
    } else {
        int r = (p - 32) >> 4, tt = (p - 32) & 15;
        if (tt < 13) {
            const float* er = emb + (size_t)tt * 128;
            const float* wc = Wrel + ((size_t)r * 128) * 128 + n;
            float acc = 0.f;
            for (int k = 0; k < 128; ++k) acc += er[k] * wc[(size_t)k * 128];
            val = acc;
        }
    }
    B0f[i] = f2bf(val);
}

// ---------------------------------------------------------------- layer-1 B fragments (k-side permuted)

__global__ void build_Bf1(const float* __restrict__ Wroot, const float* __restrict__ Wrel,
                          unsigned short* __restrict__ Bf, float* __restrict__ bnSums) {
    if (blockIdx.x < 8) bnSums[blockIdx.x * 256 + threadIdx.x] = 0.f;
    int i = blockIdx.x * 256 + threadIdx.x;   // 81920
    if (i >= 81920) return;
    int j = i & 7;
    int lane = (i >> 3) & 63;
    int t = (i >> 9) & 7;
    int ks = (i >> 12) & 3;
    int kc = i >> 14;
    int n = t * 16 + (lane & 15);
    int kcol = j * 16 + ks * 4 + (lane >> 4);
    float w;
    if (kc == 0) w = Wroot[16384 + (size_t)kcol * 128 + n];
    else {
        int r = kc - 1;
        w = Wrel[(((size_t)(4 + r) * 128) + kcol) * 128 + n];
    }
    Bf[i] = f2bf(w);
}

// ---------------------------------------------------------------- layer-0 GEMM (K=96)

__global__ __launch_bounds__(256) void gemm0_mfma(const unsigned short* __restrict__ A0,
                                                  const unsigned short* __restrict__ B0f,
                                                  const float* __restrict__ bias,
                                                  unsigned short* __restrict__ Cb,
                                                  float* __restrict__ bnSums, int M) {
    __shared__ float sred[2][4][128];
    const int tid = threadIdx.x;
    const int wv = tid >> 6, lane = tid & 63;
    const int l16 = lane & 15, quad = lane >> 4;
    const int rowbase = blockIdx.x * 128 + wv * 32;
    const int tmax = (M >> 4) - 1;
    int tile0 = blockIdx.x * 8 + wv * 2; if (tile0 > tmax) tile0 = tmax;
    int tile1 = tile0 + 1;               if (tile1 > tmax) tile1 = tmax;

    float4v acc[2][8];
    #pragma unroll
    for (int t = 0; t < 8; ++t) {
        float bv = bias[t * 16 + l16];
        float4v av = {bv, bv, bv, bv};
        acc[0][t] = av; acc[1][t] = av;
    }

    const unsigned short* bl = B0f + lane * 8;
    const unsigned short* F0 = A0 + (size_t)tile0 * 1536 + quad * 128 + l16 * 8;
    const unsigned short* F1 = A0 + (size_t)tile1 * 1536 + quad * 128 + l16 * 8;
    #pragma unroll
    for (int ks = 0; ks < 3; ++ks) {
        short8 af0 = *(const short8*)(F0 + ks * 512);
        short8 af1 = *(const short8*)(F1 + ks * 512);
        const unsigned short* bp = bl + ((ks * 8) << 9);
        #pragma unroll
        for (int t = 0; t < 8; ++t) {
            short8 bf = *(const short8*)(bp + (t << 9));
            acc[0][t] = __builtin_amdgcn_mfma_f32_16x16x32_bf16(af0, bf, acc[0][t], 0, 0, 0);
            acc[1][t] = __builtin_amdgcn_mfma_f32_16x16x32_bf16(af1, bf, acc[1][t], 0, 0, 0);
        }
    }

    #pragma unroll
    for (int h = 0; h < 2; ++h) {
        #pragma unroll
        for (int rg = 0; rg < 4; ++rg) {
            int rr = rowbase + h * 16 + quad * 4 + rg;
            if (rr < M) {
                unsigned short v[8];
                #pragma unroll
                for (int t = 0; t < 8; ++t) v[t] = f2bf(acc[h][t][rg]);
                *(uint4*)(Cb + (size_t)rr * 128 + l16 * 8) = *(uint4*)v;
            }
        }
    }
    float s[8], q[8];
    #pragma unroll
    for (int t = 0; t < 8; ++t) {
        s[t] = 0.f; q[t] = 0.f;
        #pragma unroll
        for (int h = 0; h < 2; ++h) {
            #pragma unroll
            for (int rg = 0; rg < 4; ++rg) {
                int rr = rowbase + h * 16 + quad * 4 + rg;
                if (rr < M) { float v = acc[h][t][rg]; s[t] += v; q[t] += v * v; }
            }
        }
    }
    #pragma unroll
    for (int t = 0; t < 8; ++t) {
        s[t] += __shfl_down(s[t], 32, 64); q[t] += __shfl_down(q[t], 32, 64);
        s[t] += __shfl_down(s[t], 16, 64); q[t] += __shfl_down(q[t], 16, 64);
    }
    if (lane < 16) {
        #pragma unroll
        for (int t = 0; t < 8; ++t) {
            sred[0][wv][t * 16 + l16] = s[t];
            sred[1][wv][t * 16 + l16] = q[t];
        }
    }
    __syncthreads();
    if (tid < 128) {
        float S = sred[0][0][tid] + sred[0][1][tid] + sred[0][2][tid] + sred[0][3][tid];
        float Q = sred[1][0][tid] + sred[1][1][tid] + sred[1][2][tid] + sred[1][3][tid];
        float* bnS = bnSums + ((blockIdx.x & 7) << 8);
        unsafeAtomicAdd(bnS + tid, S);
        unsafeAtomicAdd(bnS + 128 + tid, Q);
    }
}

// ---------------------------------------------------------------- FUSED layer-1: gather + GEMM
// Unroll-4 edge loop: 4 independent row loads in flight per iteration.

__global__ __launch_bounds__(256) void gather_gemm1(const unsigned short* __restrict__ hbf,
                                                    const int* __restrict__ sorted2,
                                                    const int* __restrict__ offs4,
                                                    const unsigned short* __restrict__ Bf,
                                                    const float* __restrict__ bias,
                                                    unsigned short* __restrict__ Cb,
                                                    float* __restrict__ bnSums) {
    __shared__ unsigned short rootL[2048];   // 4KB  (16B-unit swizzled)
    __shared__ unsigned short aggL[8192];    // 16KB (4 rel blocks, swizzled)
    const int tid = threadIdx.x;
    const int tile = blockIdx.x;
    {
        const int l16g = tid >> 4;
        const int cidx = tid & 15;
        const int c8 = cidx << 3;
        const int n = tile * 16 + l16g;                  // NN = 6250*16 exact
        const int pu = cidx * 16 + (l16g ^ cidx);        // swizzled unit
        uint4 ru = *(const uint4*)(hbf + (size_t)n * 128 + c8);
        *(uint4*)(rootL + pu * 8) = ru;

        const unsigned short* hb = hbf + c8;
        const int ob = n * 4;
        auto acc8 = [](float* a, uint4 u) {
            a[0] += __uint_as_float(u.x << 16); a[1] += __uint_as_float(u.x & 0xffff0000u);
            a[2] += __uint_as_float(u.y << 16); a[3] += __uint_as_float(u.y & 0xffff0000u);
            a[4] += __uint_as_float(u.z << 16); a[5] += __uint_as_float(u.z & 0xffff0000u);
            a[6] += __uint_as_float(u.w << 16); a[7] += __uint_as_float(u.w & 0xffff0000u);
        };
        #pragma unroll
        for (int r = 0; r < 4; ++r) {
            const int i0 = offs4[ob + r];
            const int i1 = offs4[ob + r + 1];
            float aA[8], aB[8];
            #pragma unroll
            for (int j = 0; j < 8; ++j) { aA[j] = 0.f; aB[j] = 0.f; }
            int i = i0;
            for (; i + 4 <= i1; i += 4) {
                int s0 = sorted2[i], s1 = sorted2[i + 1];
                int s2 = sorted2[i + 2], s3 = sorted2[i + 3];
                uint4 u0 = *(const uint4*)(hb + (size_t)s0 * 128);
                uint4 u1 = *(const uint4*)(hb + (size_t)s1 * 128);
                uint4 u2 = *(const uint4*)(hb + (size_t)s2 * 128);
                uint4 u3 = *(const uint4*)(hb + (size_t)s3 * 128);
                acc8(aA, u0); acc8(aB, u1); acc8(aA, u2); acc8(aB, u3);
            }
            if (i + 2 <= i1) {
                int s0 = sorted2[i], s1 = sorted2[i + 1];
                uint4 u0 = *(const uint4*)(hb + (size_t)s0 * 128);
                uint4 u1 = *(const uint4*)(hb + (size_t)s1 * 128);
                acc8(aA, u0); acc8(aB, u1);
                i += 2;
            }
            if (i < i1) {
                int s0 = sorted2[i];
                uint4 u0 = *(const uint4*)(hb + (size_t)s0 * 128);
                acc8(aA, u0);
            }
            const int cnt = i1 - i0;
            const float inv = 1.0f / (float)(cnt > 0 ? cnt : 1);
            unsigned short v[8];
            #pragma unroll
            for (int j = 0; j < 8; ++j) v[j] = f2bf((aA[j] + aB[j]) * inv);
            *(uint4*)(aggL + r * 2048 + pu * 8) = *(uint4*)v;
        }
    }
    __syncthreads();

    // ---- GEMM phase: wave wv handles output cols t0=2wv, t0+1
    const int wv = tid >> 6, lane = tid & 63;
    const int l16 = lane & 15, quad = lane >> 4;
    const int t0 = wv << 1;
    float4v acc0, acc1;
    {
        float b0v = bias[t0 * 16 + l16];
        float b1v = bias[(t0 + 1) * 16 + l16];
        float4v a0v = {b0v, b0v, b0v, b0v};
        float4v a1v = {b1v, b1v, b1v, b1v};
        acc0 = a0v; acc1 = a1v;
    }
    const unsigned short* bl = Bf + lane * 8;
    #pragma unroll
    for (int kc = 0; kc < 5; ++kc) {
        const unsigned short* Abase = (kc == 0) ? rootL : (aggL + (kc - 1) * 2048);
        #pragma unroll
        for (int ks = 0; ks < 4; ++ks) {
            const int C = ks * 4 + quad;
            const int p = C * 16 + (l16 ^ C);
            short8 af = *(const short8*)(Abase + p * 8);
            const unsigned short* bp = bl + (((kc * 4 + ks) * 8 + t0) << 9);
            short8 b0 = *(const short8*)(bp);
            short8 b1 = *(const short8*)(bp + 512);
            acc0 = __builtin_amdgcn_mfma_f32_16x16x32_bf16(af, b0, acc0, 0, 0, 0);
            acc1 = __builtin_amdgcn_mfma_f32_16x16x32_bf16(af, b1, acc1, 0, 0, 0);
        }
    }
    const int rowbase = tile * 16;
    #pragma unroll
    for (int rg = 0; rg < 4; ++rg) {
        int rr = rowbase + quad * 4 + rg;
        unsigned pk = (unsigned)f2bf(acc0[rg]) | ((unsigned)f2bf(acc1[rg]) << 16);
        *(unsigned*)(Cb + (size_t)rr * 128 + l16 * 8 + t0) = pk;
    }
    float s0 = 0.f, q0 = 0.f, s1 = 0.f, q1 = 0.f;
    #pragma unroll
    for (int rg = 0; rg < 4; ++rg) {
        float v0 = acc0[rg], v1 = acc1[rg];
        s0 += v0; q0 += v0 * v0; s1 += v1; q1 += v1 * v1;
    }
    s0 += __shfl_down(s0, 32, 64); q0 += __shfl_down(q0, 32, 64);
    s1 += __shfl_down(s1, 32, 64); q1 += __shfl_down(q1, 32, 64);
    s0 += __shfl_down(s0, 16, 64); q0 += __shfl_down(q0, 16, 64);
    s1 += __shfl_down(s1, 16, 64); q1 += __shfl_down(q1, 16, 64);
    if (lane < 16) {
        float* bnS = bnSums + ((tile & 7) << 8);
        unsafeAtomicAdd(bnS + t0 * 16 + l16, s0);
        unsafeAtomicAdd(bnS + 128 + t0 * 16 + l16, q0);
        unsafeAtomicAdd(bnS + (t0 + 1) * 16 + l16, s1);
        unsafeAtomicAdd(bnS + 128 + (t0 + 1) * 16 + l16, q1);
    }
}

// ---------------------------------------------------------------- BN finalize (+ optional g0 zero)

__global__ void bn_finalize(const float* __restrict__ bnSums, float* __restrict__ fin,
                            float* __restrict__ g0zero, int n) {
    const int c = threadIdx.x;   // 128
    if (g0zero) g0zero[blockIdx.x * 128 + c] = 0.f;
    if (blockIdx.x != 0) return;
    float s = 0.f, q = 0.f;
    #pragma unroll
    for (int j = 0; j < 8; ++j) { s += bnSums[j * 256 + c]; q += bnSums[j * 256 + 128 + c]; }
    const float invn = 1.0f / (float)n;
    float mu = s * invn;
    float var = q * invn - mu * mu; if (var < 0.f) var = 0.f;
    fin[c] = mu;
    fin[128 + c] = rsqrtf(var + 1e-5f);
}

// ---------------------------------------------------------------- layer-0 BN/PReLU/L2norm -> hbf

__global__ __launch_bounds__(256) void bn_apply_kernel(const unsigned short* __restrict__ Cb,
                                unsigned short* __restrict__ hbf,
                                const float* __restrict__ fin,
                                const float* __restrict__ gamma, const float* __restrict__ beta,
                                const float* __restrict__ prelu_a, int layer) {
    const int tid = threadIdx.x;
    const int row = blockIdx.x * 16 + (tid >> 4);
    const int li = tid & 15;
    const int p8 = li << 3;
    const float a = prelu_a[layer];
    uint4 u = *(const uint4*)(Cb + (size_t)row * 128 + p8);
    float v[8];
    v[0] = __uint_as_float(u.x << 16); v[1] = __uint_as_float(u.x & 0xffff0000u);
    v[2] = __uint_as_float(u.y << 16); v[3] = __uint_as_float(u.y & 0xffff0000u);
    v[4] = __uint_as_float(u.z << 16); v[5] = __uint_as_float(u.z & 0xffff0000u);
    v[6] = __uint_as_float(u.w << 16); v[7] = __uint_as_float(u.w & 0xffff0000u);
    float t[8]; float ss = 0.f;
    #pragma unroll
    for (int j = 0; j < 8; ++j) {
        int cc = j * 16 + li;
        float tv = (v[j] - fin[cc]) * fin[128 + cc] * gamma[cc] + beta[cc];
        tv = (tv >= 0.f) ? tv : a * tv;
        t[j] = tv; ss += tv * tv;
    }
    ss += __shfl_xor(ss, 1, 64);
    ss += __shfl_xor(ss, 2, 64);
    ss += __shfl_xor(ss, 4, 64);
    ss += __shfl_xor(ss, 8, 64);
    const float scale = 1.0f / fmaxf(sqrtf(ss), 1e-12f);
    unsigned short o[8];
    #pragma unroll
    for (int j = 0; j < 8; ++j) o[j] = f2bf(t[j] * scale);
    *(uint4*)(hbf + (size_t)row * 128 + p8) = *(uint4*)o;
}

// ---------------------------------------------------------------- layer-1 BN/PReLU/L2norm + fused pooling
// Writes no hbf; accumulates per-graph sums into g0 (atomic, ~1-2 per col per block).

__global__ __launch_bounds__(256) void bn_apply_pool(const unsigned short* __restrict__ Cb,
                                const float* __restrict__ fin,
                                const float* __restrict__ gamma, const float* __restrict__ beta,
                                const float* __restrict__ prelu_a,
                                const int* __restrict__ batch,
                                float* __restrict__ g0) {
    __shared__ float P[16][128];
    __shared__ int gids[16];
    const int tid = threadIdx.x;
    const int r16 = tid >> 4;
    const int li = tid & 15;
    const int row = blockIdx.x * 16 + r16;
    const int p8 = li << 3;
    if (li == 0) gids[r16] = batch[row];
    const float a = prelu_a[1];
    uint4 u = *(const uint4*)(Cb + (size_t)row * 128 + p8);
    float v[8];
    v[0] = __uint_as_float(u.x << 16); v[1] = __uint_as_float(u.x & 0xffff0000u);
    v[2] = __uint_as_float(u.y << 16); v[3] = __uint_as_float(u.y & 0xffff0000u);
    v[4] = __uint_as_float(u.z << 16); v[5] = __uint_as_float(u.z & 0xffff0000u);
    v[6] = __uint_as_float(u.w << 16); v[7] = __uint_as_float(u.w & 0xffff0000u);
    float t[8]; float ss = 0.f;
    #pragma unroll
    for (int j = 0; j < 8; ++j) {
        int cc = j * 16 + li;
        float tv = (v[j] - fin[cc]) * fin[128 + cc] * gamma[cc] + beta[cc];
        tv = (tv >= 0.f) ? tv : a * tv;
        t[j] = tv; ss += tv * tv;
    }
    ss += __shfl_xor(ss, 1, 64);
    ss += __shfl_xor(ss, 2, 64);
    ss += __shfl_xor(ss, 4, 64);
    ss += __shfl_xor(ss, 8, 64);
    const float scale = 1.0f / fmaxf(sqrtf(ss), 1e-12f);
    #pragma unroll
    for (int j = 0; j < 8; ++j) P[r16][p8 + j] = t[j] * scale;
    __syncthreads();
    if (tid < 128) {
        int cur = gids[0];
        float run = 0.f;
        #pragma unroll
        for (int rr = 0; rr < 16; ++rr) {
            int g = gids[rr];
            if (g != cur) {
                unsafeAtomicAdd(&g0[(size_t)cur * 128 + tid], run);
                run = 0.f; cur = g;
            }
            run += P[rr][tid];
        }
        unsafeAtomicAdd(&g0[(size_t)cur * 128 + tid], run);
    }
}

// ---------------------------------------------------------------- MLP (fc1 applies 1/cnt)

__global__ void fc1_kernel(const float* __restrict__ g, const float* __restrict__ w,
                           const float* __restrict__ b, const int* __restrict__ batch,
                           float* __restrict__ o) {
    const int row = blockIdx.x;   // 512
    const int j = threadIdx.x;    // 256
    const int lo = lower_bound_dev(batch, NN, row);
    const int hi = lower_bound_dev(batch, NN, row + 1);
    const int c = hi - lo;
    const float invc = 1.0f / (float)(c > 0 ? c : 1);
    float acc = 0.f;
    #pragma unroll 8
    for (int k = 0; k < 128; ++k) {
        int lk = (k & 7) * 16 + (k >> 3);         // logical feature for mem pos k
        acc += g[row * 128 + k] * w[lk * 256 + j];
    }
    o[row * 256 + j] = fmaxf(acc * invc + b[j], 0.f);
}

__global__ void fc2_kernel(const float* __restrict__ g, const float* __restrict__ w,
                           const float* __restrict__ b, float* __restrict__ o) {
    const int row = blockIdx.x;   // 512
    const int j = threadIdx.x;    // 128
    float acc = b[j];
    #pragma unroll 8
    for (int k = 0; k < 256; ++k) acc += g[row * 256 + k] * w[k * 128 + j];
    o[row * 128 + j] = fmaxf(acc, 0.f);
}

__global__ void fco_kernel(const float* __restrict__ g, const float* __restrict__ w,
                           const float* __restrict__ b, float* __restrict__ o) {
    const int row = blockIdx.x * blockDim.x + threadIdx.x;
    if (row >= NG) return;
    float acc = b[0];
    #pragma unroll 8
    for (int k = 0; k < 128; ++k) acc += g[row * 128 + k] * w[k];
    o[row] = acc;
}

// ---------------------------------------------------------------- launcher

extern "C" void kernel_launch(void* const* d_in, const int* in_sizes, int n_in,
                              void* d_out, int out_size, void* d_ws, size_t ws_size,
                              hipStream_t stream) {
    const float* x      = (const float*)d_in[0];
    const int*   eidx   = (const int*)d_in[1];
    const int*   etype  = (const int*)d_in[2];
    const int*   batch  = (const int*)d_in[3];
    const float* emb    = (const float*)d_in[4];
    const float* Wrel   = (const float*)d_in[5];
    const float* Wroot  = (const float*)d_in[6];
    const float* cbias  = (const float*)d_in[7];
    const float* gamma  = (const float*)d_in[8];
    const float* beta   = (const float*)d_in[9];
    const float* prelua = (const float*)d_in[10];
    const float* fc1w   = (const float*)d_in[11];
    const float* fc1b   = (const float*)d_in[12];
    const float* fc2w   = (const float*)d_in[13];
    const float* fc2b   = (const float*)d_in[14];
    const float* outw   = (const float*)d_in[15];
    const float* outb   = (const float*)d_in[16];
    float* out = (float*)d_out;

    const int* src = eidx;
    const int* dst = eidx + NE;

    // workspace carve-up (aligned 256B)
    char* p = (char*)d_ws;
    auto alloc = [&](size_t bytes) { char* r = p; p += (bytes + 255) & ~(size_t)255; return r; };
    unsigned short* hbf   = (unsigned short*)alloc((size_t)NN * 128 * 2);  // 25.6 MB
    unsigned short* Cb    = (unsigned short*)alloc((size_t)NN * 128 * 2);  // 25.6 MB
    char*  scratch   = (char*)alloc((size_t)24 << 20);                     // partials / A0 (sequential)
    int*   sortedSrc = (int*)alloc((size_t)NE * 4);                        // 6.4 MB
    int*   sorted2   = (int*)alloc((size_t)NE * 4);                        // 6.4 MB (rel-sorted)
    int*   srcT      = (int*)alloc((size_t)NE * 4);                        // 6.4 MB (src|type)
    int*   offs      = (int*)alloc((size_t)(NN + 1) * 4);
    int*   offs4     = (int*)alloc((size_t)(4 * NN + 1) * 4);              // 1.6 MB
    int*   bsums     = (int*)alloc(1024);
    int*   ntype     = (int*)alloc((size_t)NN * 4);
    unsigned short* Bf1 = (unsigned short*)alloc((size_t)81920 * 2);
    unsigned short* B0f = (unsigned short*)alloc((size_t)12288 * 2);
    float* bnSums  = (float*)alloc(2048 * 4);
    float* bnFin   = (float*)alloc(256 * 4);
    float* g0      = (float*)alloc((size_t)NG * 128 * 4);
    float* g1      = (float*)alloc((size_t)NG * 256 * 4);
    float* g2      = (float*)alloc((size_t)NG * 128 * 4);

    unsigned* partials = (unsigned*)scratch;          // 16.8 MB, dead after place
    unsigned short* A0 = (unsigned short*)scratch;    // 19.2 MB, built after place

    const int NBLK = (NN + 1023) / 1024;   // 98

    // ---- node types + src-type pack
    node_type_kernel<<<(NN + 255) / 256, 256, 0, stream>>>(x, ntype, NN);
    pack_src_type<<<(NE + 255) / 256, 256, 0, stream>>>(src, ntype, srcT);

    // ---- CSR build over dst (2 chunk passes, u8 counters, no global atomics)
    hist_kernel<<<dim3(BPC, NCH), 256, 0, stream>>>(dst, partials);
    hist_reduce<<<dim3(CHW / 256, NCH), 256, 0, stream>>>(partials, offs);
    scan1<<<NBLK, 256, 0, stream>>>(offs, offs, bsums, NN);
    scan2<<<1, 64, 0, stream>>>(bsums, offs, NBLK, NN);
    scan3<<<NBLK, 256, 0, stream>>>(offs, bsums, NN);
    place_kernel<<<dim3(BPC, NCH), 256, 0, stream>>>(dst, etype, srcT, offs, partials, sortedSrc);

    // ---- rel-sort segments + layer-0 A0 build (no random gathers)
    relsort_hist<<<(NN + 255) / 256, 256, 0, stream>>>(sortedSrc, offs, ntype,
                                                       sorted2, offs4, A0);

    // ---- layer 0: type-histogram GEMM
    build_B0<<<48, 256, 0, stream>>>(emb, Wroot, Wrel, B0f, bnSums);
    gemm0_mfma<<<(NN + 127) / 128, 256, 0, stream>>>(A0, B0f, cbias, Cb, bnSums, NN);
    bn_finalize<<<1, 128, 0, stream>>>(bnSums, bnFin, (float*)nullptr, NN);
    bn_apply_kernel<<<NN / 16, 256, 0, stream>>>(Cb, hbf, bnFin, gamma, beta, prelua, 0);

    // ---- layer 1: fused gather + GEMM, then BN + fused pooling
    build_Bf1<<<320, 256, 0, stream>>>(Wroot, Wrel, Bf1, bnSums);
    gather_gemm1<<<NN / 16, 256, 0, stream>>>(hbf, sorted2, offs4, Bf1, cbias + 128, Cb, bnSums);
    bn_finalize<<<512, 128, 0, stream>>>(bnSums, bnFin, g0, NN);
    bn_apply_pool<<<NN / 16, 256, 0, stream>>>(Cb, bnFin, gamma + 128, beta + 128,
                                               prelua, batch, g0);

    // ---- MLP (fc1 folds 1/cnt)
    fc1_kernel<<<NG, 256, 0, stream>>>(g0, fc1w, fc1b, batch, g1);
    fc2_kernel<<<NG, 128, 0, stream>>>(g1, fc2w, fc2b, g2);
    fco_kernel<<<2, 256, 0, stream>>>(g2, outw, outb, out);
}

// Round 12
// 374.806 us; speedup vs baseline: 1.1974x; 1.0159x over previous
//
#include <hip/hip_runtime.h>
#include <hip/hip_bf16.h>

#define NN 100000
#define NE 1600000
#define NG 512
#define CH3 65536      // keys per chunk (u8-packed counters: 16384 u32 = 64KB LDS)
#define CHW 16384      // u32 words per chunk
#define NCH 2          // ceil(100000/65536)
#define BPC 128        // blocks per chunk
#define ES 12500       // NE / BPC

// Feature-column permutation: mem position p holds logical col (p&7)*16+(p>>3).
// sortedSrc payload: src[0:17) | type[17:21) | rel[21:23).
// LDS tiles XOR-swizzled: unit = C*16 + (L^C).
// gather_gemm1 is pinned at the compulsory random-fetch floor (FETCH ~= 8 XCD x hbf);
// mask-FMA over unsorted segments == rel-sorted in time (R9 vs R10/R11), so no reorder pass.

typedef __attribute__((ext_vector_type(8))) short short8;
typedef __attribute__((ext_vector_type(4))) float float4v;

// ---------------------------------------------------------------- utilities

__device__ inline int lower_bound_dev(const int* __restrict__ a, int n, int v) {
    int lo = 0, hi = n;
    while (lo < hi) { int mid = (lo + hi) >> 1; if (a[mid] < v) lo = mid + 1; else hi = mid; }
    return lo;
}

__device__ inline unsigned short f2bf(float x) {
    unsigned u = __float_as_uint(x);
    unsigned r = (u + 0x7fffu + ((u >> 16) & 1u)) >> 16;   // RNE
    return (unsigned short)r;
}

__device__ inline float bf2f(unsigned short h) {
    return __uint_as_float((unsigned)h << 16);
}

// ---------------------------------------------------------------- node types + src-type pack

__global__ void node_type_kernel(const float* __restrict__ x, int* __restrict__ idx, int n) {
    int i = blockIdx.x * blockDim.x + threadIdx.x;
    if (i >= n) return;
    const float* row = x + (size_t)i * 13;
    int b = 0;
    #pragma unroll
    for (int t = 0; t < 13; ++t) if (row[t] > 0.5f) { b = t; }
    idx[i] = b;
}

__global__ void pack_src_type(const int* __restrict__ src, const int* __restrict__ ntype,
                              int* __restrict__ srcT) {
    int e = blockIdx.x * 256 + threadIdx.x;
    if (e >= NE) return;
    int s = src[e];
    srcT[e] = s | (ntype[s] << 17);
}

// ---------------------------------------------------------------- CSR build, key = dst (2 passes)

__global__ __launch_bounds__(256) void hist_kernel(const int* __restrict__ dst,
                                                   unsigned* __restrict__ partials) {
    __shared__ unsigned h[CHW];
    const int b = blockIdx.x, c = blockIdx.y;
    const int lo = c * CH3;
    for (int i = threadIdx.x; i < CHW; i += 256) h[i] = 0;
    __syncthreads();
    const int e0 = b * ES;
    const int e1 = (e0 + ES < NE) ? e0 + ES : NE;
    for (int e = e0 + threadIdx.x; e < e1; e += 256) {
        int k = dst[e] - lo;
        if (k >= 0 && k < CH3) atomicAdd(&h[k >> 2], 1u << ((k & 3) << 3));
    }
    __syncthreads();
    unsigned* out = partials + ((size_t)(c * BPC + b)) * CHW;
    for (int i = threadIdx.x; i < CHW; i += 256) out[i] = h[i];
}

__global__ void hist_reduce(unsigned* __restrict__ partials, int* __restrict__ counts) {
    const int c = blockIdx.y;
    const int i = blockIdx.x * 256 + threadIdx.x;   // [0, CHW)
    size_t base = (size_t)c * BPC * CHW + i;
    unsigned r0 = 0, r1 = 0, r2 = 0, r3 = 0;
    #pragma unroll 4
    for (int b = 0; b < BPC; ++b) {
        unsigned t = partials[base + (size_t)b * CHW];
        partials[base + (size_t)b * CHW] = r0 | (r1 << 8) | (r2 << 16) | (r3 << 24);
        r0 += t & 0xffu; r1 += (t >> 8) & 0xffu; r2 += (t >> 16) & 0xffu; r3 += t >> 24;
    }
    int k0 = c * CH3 + 4 * i;
    if (k0 < NN)     counts[k0]     = (int)r0;
    if (k0 + 1 < NN) counts[k0 + 1] = (int)r1;
    if (k0 + 2 < NN) counts[k0 + 2] = (int)r2;
    if (k0 + 3 < NN) counts[k0 + 3] = (int)r3;
}

__global__ __launch_bounds__(256) void scan1(const int* __restrict__ counts, int* __restrict__ offs,
                                             int* __restrict__ bsums, int n) {
    __shared__ int wsum[4];
    const int base = blockIdx.x * 1024 + threadIdx.x * 4;
    int v[4]; int loc = 0;
    #pragma unroll
    for (int j = 0; j < 4; ++j) { int idx = base + j; v[j] = (idx < n) ? counts[idx] : 0; loc += v[j]; }
    const int lane = threadIdx.x & 63, wid = threadIdx.x >> 6;
    int sc = loc;
    #pragma unroll
    for (int o = 1; o < 64; o <<= 1) { int t = __shfl_up(sc, o, 64); if (lane >= o) sc += t; }
    if (lane == 63) wsum[wid] = sc;
    __syncthreads();
    int wbase = 0;
    for (int w = 0; w < wid; ++w) wbase += wsum[w];
    int run = wbase + sc - loc;
    #pragma unroll
    for (int j = 0; j < 4; ++j) { int idx = base + j; if (idx < n) offs[idx] = run; run += v[j]; }
    if (threadIdx.x == 255) bsums[blockIdx.x] = wbase + sc;
}

__global__ void scan2(int* __restrict__ bsums, int* __restrict__ offs, int nb, int n) {
    const int lane = threadIdx.x;   // 64 threads
    int carry = 0;
    for (int base = 0; base < nb; base += 64) {
        int idx = base + lane;
        int v = (idx < nb) ? bsums[idx] : 0;
        int sc = v;
        #pragma unroll
        for (int o = 1; o < 64; o <<= 1) { int t = __shfl_up(sc, o, 64); if (lane >= o) sc += t; }
        if (idx < nb) bsums[idx] = carry + sc - v;
        int tot = __shfl(sc, 63, 64);
        carry += tot;
    }
    if (lane == 0) offs[n] = carry;
}

__global__ __launch_bounds__(256) void scan3(int* __restrict__ offs, const int* __restrict__ bsums, int n) {
    const int s = bsums[blockIdx.x];
    const int base = blockIdx.x * 1024 + threadIdx.x * 4;
    #pragma unroll
    for (int j = 0; j < 4; ++j) { int idx = base + j; if (idx < n) offs[idx] += s; }
}

// placement: LDS u8 cursors; payload = srcT | (rel<<21)
__global__ __launch_bounds__(256) void place_kernel(const int* __restrict__ dst,
                                                    const int* __restrict__ et,
                                                    const int* __restrict__ srcT,
                                                    const int* __restrict__ offs,
                                                    const unsigned* __restrict__ partials,
                                                    int* __restrict__ sortedSrc) {
    __shared__ unsigned cur[CHW];
    const int b = blockIdx.x, c = blockIdx.y;
    const int lo = c * CH3;
    const unsigned* pb = partials + ((size_t)(c * BPC + b)) * CHW;
    for (int i = threadIdx.x; i < CHW; i += 256) cur[i] = pb[i];
    __syncthreads();
    const int e0 = b * ES;
    const int e1 = (e0 + ES < NE) ? e0 + ES : NE;
    for (int e = e0 + threadIdx.x; e < e1; e += 256) {
        int key = dst[e];
        int k = key - lo;
        if (k >= 0 && k < CH3) {
            int sh = (k & 3) << 3;
            unsigned old = atomicAdd(&cur[k >> 2], 1u << sh);
            int my = (int)((old >> sh) & 0xffu);
            int pos = offs[key] + my;
            sortedSrc[pos] = srcT[e] | (et[e] << 21);
        }
    }
}

// ---------------------------------------------------------------- layer-0 A matrix (single pass)
// Type+rel carried in payload -> one streaming loop per node, no reorder, no extra writes.

__global__ __launch_bounds__(256) void hist_A0(const int* __restrict__ sortedSrc,
                                               const int* __restrict__ offs,
                                               const int* __restrict__ ntype,
                                               unsigned short* __restrict__ A0) {
    __shared__ unsigned cnt[256][13];
    const int tid = threadIdx.x;
    const int n = blockIdx.x * 256 + tid;
    if (n >= NN) return;
    #pragma unroll
    for (int t = 0; t < 13; ++t) cnt[tid][t] = 0;
    const int o0 = offs[n], o1 = offs[n + 1];
    unsigned relc = 0;
    for (int i = o0; i < o1; ++i) {
        int v = sortedSrc[i];
        int ty = (v >> 17) & 15, r = v >> 21;
        cnt[tid][ty] += 1u << (r << 3);
        relc += 1u << (r << 3);
    }
    float inv[4];
    #pragma unroll
    for (int r = 0; r < 4; ++r) {
        unsigned c = (relc >> (r << 3)) & 0xffu;
        inv[r] = 1.0f / (float)(c > 0 ? c : 1);
    }
    const int myty = ntype[n];
    const int tile = n >> 4, l16 = n & 15;
    unsigned short* base = A0 + (size_t)tile * 1536 + l16 * 8;
    #pragma unroll
    for (int ks = 0; ks < 3; ++ks) {
        #pragma unroll
        for (int quad = 0; quad < 4; ++quad) {
            unsigned short vals[8];
            #pragma unroll
            for (int j = 0; j < 8; ++j) {
                int p = ks * 32 + quad * 8 + j;
                float v;
                if (p < 32) v = (p == myty) ? 1.0f : 0.0f;
                else {
                    int r = (p - 32) >> 4, tt = (p - 32) & 15;
                    v = (tt < 13) ? (float)((cnt[tid][tt] >> (r << 3)) & 0xffu) * inv[r] : 0.0f;
                }
                vals[j] = f2bf(v);
            }
            *(uint4*)(base + ks * 512 + quad * 128) = *(uint4*)vals;
        }
    }
}

// ---------------------------------------------------------------- layer-0 B: B0 = emb @ [Wroot0; Wrel0_r]

__global__ void build_B0(const float* __restrict__ emb, const float* __restrict__ Wroot,
                         const float* __restrict__ Wrel, unsigned short* __restrict__ B0f,
                         float* __restrict__ bnSums) {
    if (blockIdx.x < 8) bnSums[blockIdx.x * 256 + threadIdx.x] = 0.f;
    int i = blockIdx.x * 256 + threadIdx.x;   // 3*8*64*8 = 12288
    if (i >= 12288) return;
    int j = i & 7;
    int lane = (i >> 3) & 63;
    int t = (i >> 9) & 7;
    int ks = i >> 12;
    int n = t * 16 + (lane & 15);
    int p = ks * 32 + (lane >> 4) * 8 + j;
    float val = 0.f;
    if (p < 32) {
        if (p < 13) {
            const float* er = emb + (size_t)p * 128;
            const float* wc = Wroot + n;
            float acc = 0.f;
            for (int k = 0; k < 128; ++k) acc += er[k] * wc[(size_t)k * 128];
            val = acc;
        }
    } else {
        int r = (p - 32) >> 4, tt = (p - 32) & 15;
        if (tt < 13) {
            const float* er = emb + (size_t)tt * 128;
            const float* wc = Wrel + ((size_t)r * 128) * 128 + n;
            float acc = 0.f;
            for (int k = 0; k < 128; ++k) acc += er[k] * wc[(size_t)k * 128];
            val = acc;
        }
    }
    B0f[i] = f2bf(val);
}

// ---------------------------------------------------------------- layer-1 B fragments (k-side permuted)

__global__ void build_Bf1(const float* __restrict__ Wroot, const float* __restrict__ Wrel,
                          unsigned short* __restrict__ Bf, float* __restrict__ bnSums) {
    if (blockIdx.x < 8) bnSums[blockIdx.x * 256 + threadIdx.x] = 0.f;
    int i = blockIdx.x * 256 + threadIdx.x;   // 81920
    if (i >= 81920) return;
    int j = i & 7;
    int lane = (i >> 3) & 63;
    int t = (i >> 9) & 7;
    int ks = (i >> 12) & 3;
    int kc = i >> 14;
    int n = t * 16 + (lane & 15);
    int kcol = j * 16 + ks * 4 + (lane >> 4);
    float w;
    if (kc == 0) w = Wroot[16384 + (size_t)kcol * 128 + n];
    else {
        int r = kc - 1;
        w = Wrel[(((size_t)(4 + r) * 128) + kcol) * 128 + n];
    }
    Bf[i] = f2bf(w);
}

// ---------------------------------------------------------------- layer-0 GEMM (K=96)

__global__ __launch_bounds__(256) void gemm0_mfma(const unsigned short* __restrict__ A0,
                                                  const unsigned short* __restrict__ B0f,
                                                  const float* __restrict__ bias,
                                                  unsigned short* __restrict__ Cb,
                                                  float* __restrict__ bnSums, int M) {
    __shared__ float sred[2][4][128];
    const int tid = threadIdx.x;
    const int wv = tid >> 6, lane = tid & 63;
    const int l16 = lane & 15, quad = lane >> 4;
    const int rowbase = blockIdx.x * 128 + wv * 32;
    const int tmax = (M >> 4) - 1;
    int tile0 = blockIdx.x * 8 + wv * 2; if (tile0 > tmax) tile0 = tmax;
    int tile1 = tile0 + 1;               if (tile1 > tmax) tile1 = tmax;

    float4v acc[2][8];
    #pragma unroll
    for (int t = 0; t < 8; ++t) {
        float bv = bias[t * 16 + l16];
        float4v av = {bv, bv, bv, bv};
        acc[0][t] = av; acc[1][t] = av;
    }

    const unsigned short* bl = B0f + lane * 8;
    const unsigned short* F0 = A0 + (size_t)tile0 * 1536 + quad * 128 + l16 * 8;
    const unsigned short* F1 = A0 + (size_t)tile1 * 1536 + quad * 128 + l16 * 8;
    #pragma unroll
    for (int ks = 0; ks < 3; ++ks) {
        short8 af0 = *(const short8*)(F0 + ks * 512);
        short8 af1 = *(const short8*)(F1 + ks * 512);
        const unsigned short* bp = bl + ((ks * 8) << 9);
        #pragma unroll
        for (int t = 0; t < 8; ++t) {
            short8 bf = *(const short8*)(bp + (t << 9));
            acc[0][t] = __builtin_amdgcn_mfma_f32_16x16x32_bf16(af0, bf, acc[0][t], 0, 0, 0);
            acc[1][t] = __builtin_amdgcn_mfma_f32_16x16x32_bf16(af1, bf, acc[1][t], 0, 0, 0);
        }
    }

    #pragma unroll
    for (int h = 0; h < 2; ++h) {
        #pragma unroll
        for (int rg = 0; rg < 4; ++rg) {
            int rr = rowbase + h * 16 + quad * 4 + rg;
            if (rr < M) {
                unsigned short v[8];
                #pragma unroll
                for (int t = 0; t < 8; ++t) v[t] = f2bf(acc[h][t][rg]);
                *(uint4*)(Cb + (size_t)rr * 128 + l16 * 8) = *(uint4*)v;
            }
        }
    }
    float s[8], q[8];
    #pragma unroll
    for (int t = 0; t < 8; ++t) {
        s[t] = 0.f; q[t] = 0.f;
        #pragma unroll
        for (int h = 0; h < 2; ++h) {
            #pragma unroll
            for (int rg = 0; rg < 4; ++rg) {
                int rr = rowbase + h * 16 + quad * 4 + rg;
                if (rr < M) { float v = acc[h][t][rg]; s[t] += v; q[t] += v * v; }
            }
        }
    }
    #pragma unroll
    for (int t = 0; t < 8; ++t) {
        s[t] += __shfl_down(s[t], 32, 64); q[t] += __shfl_down(q[t], 32, 64);
        s[t] += __shfl_down(s[t], 16, 64); q[t] += __shfl_down(q[t], 16, 64);
    }
    if (lane < 16) {
        #pragma unroll
        for (int t = 0; t < 8; ++t) {
            sred[0][wv][t * 16 + l16] = s[t];
            sred[1][wv][t * 16 + l16] = q[t];
        }
    }
    __syncthreads();
    if (tid < 128) {
        float S = sred[0][0][tid] + sred[0][1][tid] + sred[0][2][tid] + sred[0][3][tid];
        float Q = sred[1][0][tid] + sred[1][1][tid] + sred[1][2][tid] + sred[1][3][tid];
        float* bnS = bnSums + ((blockIdx.x & 7) << 8);
        unsafeAtomicAdd(bnS + tid, S);
        unsafeAtomicAdd(bnS + 128 + tid, Q);
    }
}

// ---------------------------------------------------------------- FUSED layer-1: gather + GEMM
// Mask-FMA over unsorted segments (rel in payload), unroll-4 loads in flight.

__global__ __launch_bounds__(256) void gather_gemm1(const unsigned short* __restrict__ hbf,
                                                    const int* __restrict__ sortedSrc,
                                                    const int* __restrict__ offs,
                                                    const unsigned short* __restrict__ Bf,
                                                    const float* __restrict__ bias,
                                                    unsigned short* __restrict__ Cb,
                                                    float* __restrict__ bnSums) {
    __shared__ unsigned short rootL[2048];   // 4KB  (16B-unit swizzled)
    __shared__ unsigned short aggL[8192];    // 16KB (4 rel blocks, swizzled)
    const int tid = threadIdx.x;
    const int tile = blockIdx.x;
    {
        const int l16g = tid >> 4;
        const int cidx = tid & 15;
        const int c8 = cidx << 3;
        const int n = tile * 16 + l16g;                  // NN = 6250*16 exact
        const int pu = cidx * 16 + (l16g ^ cidx);        // swizzled unit
        uint4 ru = *(const uint4*)(hbf + (size_t)n * 128 + c8);
        *(uint4*)(rootL + pu * 8) = ru;

        const unsigned short* hb = hbf + c8;
        const int o0 = offs[n], o1 = offs[n + 1];

        float a0[8], a1[8], a2[8], a3[8];
        #pragma unroll
        for (int j = 0; j < 8; ++j) { a0[j] = 0.f; a1[j] = 0.f; a2[j] = 0.f; a3[j] = 0.f; }
        float c0 = 0.f, c1 = 0.f, c2 = 0.f, c3 = 0.f;

        auto body = [&](int v, uint4 u) {
            int r = v >> 21;
            float f[8];
            f[0] = __uint_as_float(u.x << 16); f[1] = __uint_as_float(u.x & 0xffff0000u);
            f[2] = __uint_as_float(u.y << 16); f[3] = __uint_as_float(u.y & 0xffff0000u);
            f[4] = __uint_as_float(u.z << 16); f[5] = __uint_as_float(u.z & 0xffff0000u);
            f[6] = __uint_as_float(u.w << 16); f[7] = __uint_as_float(u.w & 0xffff0000u);
            float m0 = (r == 0) ? 1.f : 0.f, m1 = (r == 1) ? 1.f : 0.f;
            float m2 = (r == 2) ? 1.f : 0.f, m3 = (r == 3) ? 1.f : 0.f;
            c0 += m0; c1 += m1; c2 += m2; c3 += m3;
            #pragma unroll
            for (int j = 0; j < 8; ++j) {
                a0[j] = fmaf(m0, f[j], a0[j]);
                a1[j] = fmaf(m1, f[j], a1[j]);
                a2[j] = fmaf(m2, f[j], a2[j]);
                a3[j] = fmaf(m3, f[j], a3[j]);
            }
        };

        int i = o0;
        for (; i + 4 <= o1; i += 4) {
            int v0 = sortedSrc[i], v1 = sortedSrc[i + 1];
            int v2 = sortedSrc[i + 2], v3 = sortedSrc[i + 3];
            uint4 u0 = *(const uint4*)(hb + (size_t)(v0 & 0x1ffff) * 128);
            uint4 u1 = *(const uint4*)(hb + (size_t)(v1 & 0x1ffff) * 128);
            uint4 u2 = *(const uint4*)(hb + (size_t)(v2 & 0x1ffff) * 128);
            uint4 u3 = *(const uint4*)(hb + (size_t)(v3 & 0x1ffff) * 128);
            body(v0, u0); body(v1, u1); body(v2, u2); body(v3, u3);
        }
        if (i + 2 <= o1) {
            int v0 = sortedSrc[i], v1 = sortedSrc[i + 1];
            uint4 u0 = *(const uint4*)(hb + (size_t)(v0 & 0x1ffff) * 128);
            uint4 u1 = *(const uint4*)(hb + (size_t)(v1 & 0x1ffff) * 128);
            body(v0, u0); body(v1, u1);
            i += 2;
        }
        if (i < o1) {
            int v0 = sortedSrc[i];
            uint4 u0 = *(const uint4*)(hb + (size_t)(v0 & 0x1ffff) * 128);
            body(v0, u0);
        }

        const float i0 = 1.f / fmaxf(c0, 1.f), i1 = 1.f / fmaxf(c1, 1.f);
        const float i2 = 1.f / fmaxf(c2, 1.f), i3 = 1.f / fmaxf(c3, 1.f);
        unsigned short* bp = aggL + pu * 8;
        auto pack = [&](float* a, float inv, unsigned short* dp) {
            unsigned short v[8];
            #pragma unroll
            for (int j = 0; j < 8; ++j) v[j] = f2bf(a[j] * inv);
            *(uint4*)dp = *(uint4*)v;
        };
        pack(a0, i0, bp);
        pack(a1, i1, bp + 2048);
        pack(a2, i2, bp + 4096);
        pack(a3, i3, bp + 6144);
    }
    __syncthreads();

    // ---- GEMM phase: wave wv handles output cols t0=2wv, t0+1
    const int wv = tid >> 6, lane = tid & 63;
    const int l16 = lane & 15, quad = lane >> 4;
    const int t0 = wv << 1;
    float4v acc0, acc1;
    {
        float b0v = bias[t0 * 16 + l16];
        float b1v = bias[(t0 + 1) * 16 + l16];
        float4v a0v = {b0v, b0v, b0v, b0v};
        float4v a1v = {b1v, b1v, b1v, b1v};
        acc0 = a0v; acc1 = a1v;
    }
    const unsigned short* bl = Bf + lane * 8;
    #pragma unroll
    for (int kc = 0; kc < 5; ++kc) {
        const unsigned short* Abase = (kc == 0) ? rootL : (aggL + (kc - 1) * 2048);
        #pragma unroll
        for (int ks = 0; ks < 4; ++ks) {
            const int C = ks * 4 + quad;
            const int p = C * 16 + (l16 ^ C);
            short8 af = *(const short8*)(Abase + p * 8);
            const unsigned short* bp = bl + (((kc * 4 + ks) * 8 + t0) << 9);
            short8 b0 = *(const short8*)(bp);
            short8 b1 = *(const short8*)(bp + 512);
            acc0 = __builtin_amdgcn_mfma_f32_16x16x32_bf16(af, b0, acc0, 0, 0, 0);
            acc1 = __builtin_amdgcn_mfma_f32_16x16x32_bf16(af, b1, acc1, 0, 0, 0);
        }
    }
    const int rowbase = tile * 16;
    #pragma unroll
    for (int rg = 0; rg < 4; ++rg) {
        int rr = rowbase + quad * 4 + rg;
        unsigned pk = (unsigned)f2bf(acc0[rg]) | ((unsigned)f2bf(acc1[rg]) << 16);
        *(unsigned*)(Cb + (size_t)rr * 128 + l16 * 8 + t0) = pk;
    }
    float s0 = 0.f, q0 = 0.f, s1 = 0.f, q1 = 0.f;
    #pragma unroll
    for (int rg = 0; rg < 4; ++rg) {
        float v0 = acc0[rg], v1 = acc1[rg];
        s0 += v0; q0 += v0 * v0; s1 += v1; q1 += v1 * v1;
    }
    s0 += __shfl_down(s0, 32, 64); q0 += __shfl_down(q0, 32, 64);
    s1 += __shfl_down(s1, 32, 64); q1 += __shfl_down(q1, 32, 64);
    s0 += __shfl_down(s0, 16, 64); q0 += __shfl_down(q0, 16, 64);
    s1 += __shfl_down(s1, 16, 64); q1 += __shfl_down(q1, 16, 64);
    if (lane < 16) {
        float* bnS = bnSums + ((tile & 7) << 8);
        unsafeAtomicAdd(bnS + t0 * 16 + l16, s0);
        unsafeAtomicAdd(bnS + 128 + t0 * 16 + l16, q0);
        unsafeAtomicAdd(bnS + (t0 + 1) * 16 + l16, s1);
        unsafeAtomicAdd(bnS + 128 + (t0 + 1) * 16 + l16, q1);
    }
}

// ---------------------------------------------------------------- BN finalize (+ optional g0 zero)

__global__ void bn_finalize(const float* __restrict__ bnSums, float* __restrict__ fin,
                            float* __restrict__ g0zero, int n) {
    const int c = threadIdx.x;   // 128
    if (g0zero) g0zero[blockIdx.x * 128 + c] = 0.f;
    if (blockIdx.x != 0) return;
    float s = 0.f, q = 0.f;
    #pragma unroll
    for (int j = 0; j < 8; ++j) { s += bnSums[j * 256 + c]; q += bnSums[j * 256 + 128 + c]; }
    const float invn = 1.0f / (float)n;
    float mu = s * invn;
    float var = q * invn - mu * mu; if (var < 0.f) var = 0.f;
    fin[c] = mu;
    fin[128 + c] = rsqrtf(var + 1e-5f);
}

// ---------------------------------------------------------------- layer-0 BN/PReLU/L2norm -> hbf

__global__ __launch_bounds__(256) void bn_apply_kernel(const unsigned short* __restrict__ Cb,
                                unsigned short* __restrict__ hbf,
                                const float* __restrict__ fin,
                                const float* __restrict__ gamma, const float* __restrict__ beta,
                                const float* __restrict__ prelu_a, int layer) {
    const int tid = threadIdx.x;
    const int row = blockIdx.x * 16 + (tid >> 4);
    const int li = tid & 15;
    const int p8 = li << 3;
    const float a = prelu_a[layer];
    uint4 u = *(const uint4*)(Cb + (size_t)row * 128 + p8);
    float v[8];
    v[0] = __uint_as_float(u.x << 16); v[1] = __uint_as_float(u.x & 0xffff0000u);
    v[2] = __uint_as_float(u.y << 16); v[3] = __uint_as_float(u.y & 0xffff0000u);
    v[4] = __uint_as_float(u.z << 16); v[5] = __uint_as_float(u.z & 0xffff0000u);
    v[6] = __uint_as_float(u.w << 16); v[7] = __uint_as_float(u.w & 0xffff0000u);
    float t[8]; float ss = 0.f;
    #pragma unroll
    for (int j = 0; j < 8; ++j) {
        int cc = j * 16 + li;
        float tv = (v[j] - fin[cc]) * fin[128 + cc] * gamma[cc] + beta[cc];
        tv = (tv >= 0.f) ? tv : a * tv;
        t[j] = tv; ss += tv * tv;
    }
    ss += __shfl_xor(ss, 1, 64);
    ss += __shfl_xor(ss, 2, 64);
    ss += __shfl_xor(ss, 4, 64);
    ss += __shfl_xor(ss, 8, 64);
    const float scale = 1.0f / fmaxf(sqrtf(ss), 1e-12f);
    unsigned short o[8];
    #pragma unroll
    for (int j = 0; j < 8; ++j) o[j] = f2bf(t[j] * scale);
    *(uint4*)(hbf + (size_t)row * 128 + p8) = *(uint4*)o;
}

// ---------------------------------------------------------------- layer-1 BN/PReLU/L2norm + fused pooling

__global__ __launch_bounds__(256) void bn_apply_pool(const unsigned short* __restrict__ Cb,
                                const float* __restrict__ fin,
                                const float* __restrict__ gamma, const float* __restrict__ beta,
                                const float* __restrict__ prelu_a,
                                const int* __restrict__ batch,
                                float* __restrict__ g0) {
    __shared__ float P[16][128];
    __shared__ int gids[16];
    const int tid = threadIdx.x;
    const int r16 = tid >> 4;
    const int li = tid & 15;
    const int row = blockIdx.x * 16 + r16;
    const int p8 = li << 3;
    if (li == 0) gids[r16] = batch[row];
    const float a = prelu_a[1];
    uint4 u = *(const uint4*)(Cb + (size_t)row * 128 + p8);
    float v[8];
    v[0] = __uint_as_float(u.x << 16); v[1] = __uint_as_float(u.x & 0xffff0000u);
    v[2] = __uint_as_float(u.y << 16); v[3] = __uint_as_float(u.y & 0xffff0000u);
    v[4] = __uint_as_float(u.z << 16); v[5] = __uint_as_float(u.z & 0xffff0000u);
    v[6] = __uint_as_float(u.w << 16); v[7] = __uint_as_float(u.w & 0xffff0000u);
    float t[8]; float ss = 0.f;
    #pragma unroll
    for (int j = 0; j < 8; ++j) {
        int cc = j * 16 + li;
        float tv = (v[j] - fin[cc]) * fin[128 + cc] * gamma[cc] + beta[cc];
        tv = (tv >= 0.f) ? tv : a * tv;
        t[j] = tv; ss += tv * tv;
    }
    ss += __shfl_xor(ss, 1, 64);
    ss += __shfl_xor(ss, 2, 64);
    ss += __shfl_xor(ss, 4, 64);
    ss += __shfl_xor(ss, 8, 64);
    const float scale = 1.0f / fmaxf(sqrtf(ss), 1e-12f);
    #pragma unroll
    for (int j = 0; j < 8; ++j) P[r16][p8 + j] = t[j] * scale;
    __syncthreads();
    if (tid < 128) {
        int cur = gids[0];
        float run = 0.f;
        #pragma unroll
        for (int rr = 0; rr < 16; ++rr) {
            int g = gids[rr];
            if (g != cur) {
                unsafeAtomicAdd(&g0[(size_t)cur * 128 + tid], run);
                run = 0.f; cur = g;
            }
            run += P[rr][tid];
        }
        unsafeAtomicAdd(&g0[(size_t)cur * 128 + tid], run);
    }
}

// ---------------------------------------------------------------- MLP (fc1 applies 1/cnt)

__global__ void fc1_kernel(const float* __restrict__ g, const float* __restrict__ w,
                           const float* __restrict__ b, const int* __restrict__ batch,
                           float* __restrict__ o) {
    const int row = blockIdx.x;   // 512
    const int j = threadIdx.x;    // 256
    const int lo = lower_bound_dev(batch, NN, row);
    const int hi = lower_bound_dev(batch, NN, row + 1);
    const int c = hi - lo;
    const float invc = 1.0f / (float)(c > 0 ? c : 1);
    float acc = 0.f;
    #pragma unroll 8
    for (int k = 0; k < 128; ++k) {
        int lk = (k & 7) * 16 + (k >> 3);         // logical feature for mem pos k
        acc += g[row * 128 + k] * w[lk * 256 + j];
    }
    o[row * 256 + j] = fmaxf(acc * invc + b[j], 0.f);
}

__global__ void fc2_kernel(const float* __restrict__ g, const float* __restrict__ w,
                           const float* __restrict__ b, float* __restrict__ o) {
    const int row = blockIdx.x;   // 512
    const int j = threadIdx.x;    // 128
    float acc = b[j];
    #pragma unroll 8
    for (int k = 0; k < 256; ++k) acc += g[row * 256 + k] * w[k * 128 + j];
    o[row * 128 + j] = fmaxf(acc, 0.f);
}

__global__ void fco_kernel(const float* __restrict__ g, const float* __restrict__ w,
                           const float* __restrict__ b, float* __restrict__ o) {
    const int row = blockIdx.x * blockDim.x + threadIdx.x;
    if (row >= NG) return;
    float acc = b[0];
    #pragma unroll 8
    for (int k = 0; k < 128; ++k) acc += g[row * 128 + k] * w[k];
    o[row] = acc;
}

// ---------------------------------------------------------------- launcher

extern "C" void kernel_launch(void* const* d_in, const int* in_sizes, int n_in,
                              void* d_out, int out_size, void* d_ws, size_t ws_size,
                              hipStream_t stream) {
    const float* x      = (const float*)d_in[0];
    const int*   eidx   = (const int*)d_in[1];
    const int*   etype  = (const int*)d_in[2];
    const int*   batch  = (const int*)d_in[3];
    const float* emb    = (const float*)d_in[4];
    const float* Wrel   = (const float*)d_in[5];
    const float* Wroot  = (const float*)d_in[6];
    const float* cbias  = (const float*)d_in[7];
    const float* gamma  = (const float*)d_in[8];
    const float* beta   = (const float*)d_in[9];
    const float* prelua = (const float*)d_in[10];
    const float* fc1w   = (const float*)d_in[11];
    const float* fc1b   = (const float*)d_in[12];
    const float* fc2w   = (const float*)d_in[13];
    const float* fc2b   = (const float*)d_in[14];
    const float* outw   = (const float*)d_in[15];
    const float* outb   = (const float*)d_in[16];
    float* out = (float*)d_out;

    const int* src = eidx;
    const int* dst = eidx + NE;

    // workspace carve-up (aligned 256B)
    char* p = (char*)d_ws;
    auto alloc = [&](size_t bytes) { char* r = p; p += (bytes + 255) & ~(size_t)255; return r; };
    unsigned short* hbf   = (unsigned short*)alloc((size_t)NN * 128 * 2);  // 25.6 MB
    unsigned short* Cb    = (unsigned short*)alloc((size_t)NN * 128 * 2);  // 25.6 MB
    char*  scratch   = (char*)alloc((size_t)24 << 20);                     // partials / A0 (sequential)
    int*   sortedSrc = (int*)alloc((size_t)NE * 4);                        // 6.4 MB
    int*   srcT      = (int*)alloc((size_t)NE * 4);                        // 6.4 MB (src|type)
    int*   offs      = (int*)alloc((size_t)(NN + 1) * 4);
    int*   bsums     = (int*)alloc(1024);
    int*   ntype     = (int*)alloc((size_t)NN * 4);
    unsigned short* Bf1 = (unsigned short*)alloc((size_t)81920 * 2);
    unsigned short* B0f = (unsigned short*)alloc((size_t)12288 * 2);
    float* bnSums  = (float*)alloc(2048 * 4);
    float* bnFin   = (float*)alloc(256 * 4);
    float* g0      = (float*)alloc((size_t)NG * 128 * 4);
    float* g1      = (float*)alloc((size_t)NG * 256 * 4);
    float* g2      = (float*)alloc((size_t)NG * 128 * 4);

    unsigned* partials = (unsigned*)scratch;          // 16.8 MB, dead after place
    unsigned short* A0 = (unsigned short*)scratch;    // 19.2 MB, built after place

    const int NBLK = (NN + 1023) / 1024;   // 98

    // ---- node types + src-type pack
    node_type_kernel<<<(NN + 255) / 256, 256, 0, stream>>>(x, ntype, NN);
    pack_src_type<<<(NE + 255) / 256, 256, 0, stream>>>(src, ntype, srcT);

    // ---- CSR build over dst (2 chunk passes, u8 counters, no global atomics)
    hist_kernel<<<dim3(BPC, NCH), 256, 0, stream>>>(dst, partials);
    hist_reduce<<<dim3(CHW / 256, NCH), 256, 0, stream>>>(partials, offs);
    scan1<<<NBLK, 256, 0, stream>>>(offs, offs, bsums, NN);
    scan2<<<1, 64, 0, stream>>>(bsums, offs, NBLK, NN);
    scan3<<<NBLK, 256, 0, stream>>>(offs, bsums, NN);
    place_kernel<<<dim3(BPC, NCH), 256, 0, stream>>>(dst, etype, srcT, offs, partials, sortedSrc);

    // ---- layer-0 A0 build (single streaming pass; type+rel in payload)
    hist_A0<<<(NN + 255) / 256, 256, 0, stream>>>(sortedSrc, offs, ntype, A0);

    // ---- layer 0: type-histogram GEMM
    build_B0<<<48, 256, 0, stream>>>(emb, Wroot, Wrel, B0f, bnSums);
    gemm0_mfma<<<(NN + 127) / 128, 256, 0, stream>>>(A0, B0f, cbias, Cb, bnSums, NN);
    bn_finalize<<<1, 128, 0, stream>>>(bnSums, bnFin, (float*)nullptr, NN);
    bn_apply_kernel<<<NN / 16, 256, 0, stream>>>(Cb, hbf, bnFin, gamma, beta, prelua, 0);

    // ---- layer 1: fused gather + GEMM (mask-FMA, no reorder), then BN + fused pooling
    build_Bf1<<<320, 256, 0, stream>>>(Wroot, Wrel, Bf1, bnSums);
    gather_gemm1<<<NN / 16, 256, 0, stream>>>(hbf, sortedSrc, offs, Bf1, cbias + 128, Cb, bnSums);
    bn_finalize<<<512, 128, 0, stream>>>(bnSums, bnFin, g0, NN);
    bn_apply_pool<<<NN / 16, 256, 0, stream>>>(Cb, bnFin, gamma + 128, beta + 128,
                                               prelua, batch, g0);

    // ---- MLP (fc1 folds 1/cnt)
    fc1_kernel<<<NG, 256, 0, stream>>>(g0, fc1w, fc1b, batch, g1);
    fc2_kernel<<<NG, 128, 0, stream>>>(g1, fc2w, fc2b, g2);
    fco_kernel<<<2, 256, 0, stream>>>(g2, outw, outb, out);
}

// Round 13
// 359.049 us; speedup vs baseline: 1.2499x; 1.0439x over previous
//
#include <hip/hip_runtime.h>
#include <hip/hip_bf16.h>

#define NN 100000
#define NE 1600000
#define NG 512
#define CH3 65536      // keys per chunk (u8-packed counters: 16384 u32 = 64KB LDS)
#define CHW 16384      // u32 words per chunk
#define NCH 2          // ceil(100000/65536)
#define BPC 128        // blocks per chunk
#define ES 12500       // NE / BPC

// Feature-column permutation: mem position p holds logical col (p&7)*16+(p>>3).
// sortedSrc payload: src[0:17) | type[17:21) | rel[21:23).
// gather_gemm1 is pinned at the compulsory random-fetch floor (FETCH ~= 8 XCD x hbf,
// ~2.27 TB/s across 4 structural variants R9-R12) — do not touch.

typedef __attribute__((ext_vector_type(8))) short short8;
typedef __attribute__((ext_vector_type(4))) float float4v;

// ---------------------------------------------------------------- utilities

__device__ inline int lower_bound_dev(const int* __restrict__ a, int n, int v) {
    int lo = 0, hi = n;
    while (lo < hi) { int mid = (lo + hi) >> 1; if (a[mid] < v) lo = mid + 1; else hi = mid; }
    return lo;
}

__device__ inline unsigned short f2bf(float x) {
    unsigned u = __float_as_uint(x);
    unsigned r = (u + 0x7fffu + ((u >> 16) & 1u)) >> 16;   // RNE
    return (unsigned short)r;
}

__device__ inline float bf2f(unsigned short h) {
    return __uint_as_float((unsigned)h << 16);
}

// ---------------------------------------------------------------- node types

__global__ void node_type_kernel(const float* __restrict__ x, int* __restrict__ idx, int n) {
    int i = blockIdx.x * blockDim.x + threadIdx.x;
    if (i >= n) return;
    const float* row = x + (size_t)i * 13;
    int b = 0;
    #pragma unroll
    for (int t = 0; t < 13; ++t) if (row[t] > 0.5f) { b = t; }
    idx[i] = b;
}

// ---------------------------------------------------------------- fused weight prep (layer0 + layer1) + bnSums zero
// blocks [0,320): Bf1 (81920 elems).  blocks [320,368): B0f (12288 elems).

__global__ void build_weights(const float* __restrict__ emb, const float* __restrict__ Wroot,
                              const float* __restrict__ Wrel,
                              unsigned short* __restrict__ Bf, unsigned short* __restrict__ B0f,
                              float* __restrict__ bnSums) {
    if (blockIdx.x < 8) bnSums[blockIdx.x * 256 + threadIdx.x] = 0.f;
    int i = blockIdx.x * 256 + threadIdx.x;
    if (i < 81920) {
        // layer-1 fragments, k-side permuted: kcol = j*16 + ks*4 + quad
        int j = i & 7;
        int lane = (i >> 3) & 63;
        int t = (i >> 9) & 7;
        int ks = (i >> 12) & 3;
        int kc = i >> 14;
        int n = t * 16 + (lane & 15);
        int kcol = j * 16 + ks * 4 + (lane >> 4);
        float w;
        if (kc == 0) w = Wroot[16384 + (size_t)kcol * 128 + n];
        else {
            int r = kc - 1;
            w = Wrel[(((size_t)(4 + r) * 128) + kcol) * 128 + n];
        }
        Bf[i] = f2bf(w);
    } else {
        int i0 = i - 81920;          // [0, 12288)
        int j = i0 & 7;
        int lane = (i0 >> 3) & 63;
        int t = (i0 >> 9) & 7;
        int ks = i0 >> 12;
        int n = t * 16 + (lane & 15);
        int p = ks * 32 + (lane >> 4) * 8 + j;
        float val = 0.f;
        if (p < 32) {
            if (p < 13) {
                const float* er = emb + (size_t)p * 128;
                const float* wc = Wroot + n;
                float acc = 0.f;
                for (int k = 0; k < 128; ++k) acc += er[k] * wc[(size_t)k * 128];
                val = acc;
            }
        } else {
            int r = (p - 32) >> 4, tt = (p - 32) & 15;
            if (tt < 13) {
                const float* er = emb + (size_t)tt * 128;
                const float* wc = Wrel + ((size_t)r * 128) * 128 + n;
                float acc = 0.f;
                for (int k = 0; k < 128; ++k) acc += er[k] * wc[(size_t)k * 128];
                val = acc;
            }
        }
        B0f[i0] = f2bf(val);
    }
}

// ---------------------------------------------------------------- CSR build, key = dst (2 passes)
// chunk-0 blocks also pack srcT = src | type<<17 | rel<<21 for their edge slice.

__global__ __launch_bounds__(256) void hist_kernel(const int* __restrict__ dst,
                                                   const int* __restrict__ src,
                                                   const int* __restrict__ et,
                                                   const int* __restrict__ ntype,
                                                   int* __restrict__ srcT,
                                                   unsigned* __restrict__ partials) {
    __shared__ unsigned h[CHW];
    const int b = blockIdx.x, c = blockIdx.y;
    const int lo = c * CH3;
    for (int i = threadIdx.x; i < CHW; i += 256) h[i] = 0;
    __syncthreads();
    const int e0 = b * ES;
    const int e1 = (e0 + ES < NE) ? e0 + ES : NE;
    if (c == 0) {
        for (int e = e0 + threadIdx.x; e < e1; e += 256) {
            int k = dst[e] - lo;
            if (k >= 0 && k < CH3) atomicAdd(&h[k >> 2], 1u << ((k & 3) << 3));
            int s = src[e];
            srcT[e] = s | (ntype[s] << 17) | (et[e] << 21);
        }
    } else {
        for (int e = e0 + threadIdx.x; e < e1; e += 256) {
            int k = dst[e] - lo;
            if (k >= 0 && k < CH3) atomicAdd(&h[k >> 2], 1u << ((k & 3) << 3));
        }
    }
    __syncthreads();
    unsigned* out = partials + ((size_t)(c * BPC + b)) * CHW;
    for (int i = threadIdx.x; i < CHW; i += 256) out[i] = h[i];
}

__global__ void hist_reduce(unsigned* __restrict__ partials, int* __restrict__ counts) {
    const int c = blockIdx.y;
    const int i = blockIdx.x * 256 + threadIdx.x;   // [0, CHW)
    size_t base = (size_t)c * BPC * CHW + i;
    unsigned r0 = 0, r1 = 0, r2 = 0, r3 = 0;
    #pragma unroll 4
    for (int b = 0; b < BPC; ++b) {
        unsigned t = partials[base + (size_t)b * CHW];
        partials[base + (size_t)b * CHW] = r0 | (r1 << 8) | (r2 << 16) | (r3 << 24);
        r0 += t & 0xffu; r1 += (t >> 8) & 0xffu; r2 += (t >> 16) & 0xffu; r3 += t >> 24;
    }
    int k0 = c * CH3 + 4 * i;
    if (k0 < NN)     counts[k0]     = (int)r0;
    if (k0 + 1 < NN) counts[k0 + 1] = (int)r1;
    if (k0 + 2 < NN) counts[k0 + 2] = (int)r2;
    if (k0 + 3 < NN) counts[k0 + 3] = (int)r3;
}

__global__ __launch_bounds__(256) void scan1(const int* __restrict__ counts, int* __restrict__ offs,
                                             int* __restrict__ bsums, int n) {
    __shared__ int wsum[4];
    const int base = blockIdx.x * 1024 + threadIdx.x * 4;
    int v[4]; int loc = 0;
    #pragma unroll
    for (int j = 0; j < 4; ++j) { int idx = base + j; v[j] = (idx < n) ? counts[idx] : 0; loc += v[j]; }
    const int lane = threadIdx.x & 63, wid = threadIdx.x >> 6;
    int sc = loc;
    #pragma unroll
    for (int o = 1; o < 64; o <<= 1) { int t = __shfl_up(sc, o, 64); if (lane >= o) sc += t; }
    if (lane == 63) wsum[wid] = sc;
    __syncthreads();
    int wbase = 0;
    for (int w = 0; w < wid; ++w) wbase += wsum[w];
    int run = wbase + sc - loc;
    #pragma unroll
    for (int j = 0; j < 4; ++j) { int idx = base + j; if (idx < n) offs[idx] = run; run += v[j]; }
    if (threadIdx.x == 255) bsums[blockIdx.x] = wbase + sc;
}

__global__ void scan2(int* __restrict__ bsums, int* __restrict__ offs, int nb, int n) {
    const int lane = threadIdx.x;   // 64 threads
    int carry = 0;
    for (int base = 0; base < nb; base += 64) {
        int idx = base + lane;
        int v = (idx < nb) ? bsums[idx] : 0;
        int sc = v;
        #pragma unroll
        for (int o = 1; o < 64; o <<= 1) { int t = __shfl_up(sc, o, 64); if (lane >= o) sc += t; }
        if (idx < nb) bsums[idx] = carry + sc - v;
        int tot = __shfl(sc, 63, 64);
        carry += tot;
    }
    if (lane == 0) offs[n] = carry;
}

__global__ __launch_bounds__(256) void scan3(int* __restrict__ offs, const int* __restrict__ bsums, int n) {
    const int s = bsums[blockIdx.x];
    const int base = blockIdx.x * 1024 + threadIdx.x * 4;
    #pragma unroll
    for (int j = 0; j < 4; ++j) { int idx = base + j; if (idx < n) offs[idx] += s; }
}

// placement: LDS u8 cursors; payload = srcT (type+rel already packed)
__global__ __launch_bounds__(256) void place_kernel(const int* __restrict__ dst,
                                                    const int* __restrict__ srcT,
                                                    const int* __restrict__ offs,
                                                    const unsigned* __restrict__ partials,
                                                    int* __restrict__ sortedSrc) {
    __shared__ unsigned cur[CHW];
    const int b = blockIdx.x, c = blockIdx.y;
    const int lo = c * CH3;
    const unsigned* pb = partials + ((size_t)(c * BPC + b)) * CHW;
    for (int i = threadIdx.x; i < CHW; i += 256) cur[i] = pb[i];
    __syncthreads();
    const int e0 = b * ES;
    const int e1 = (e0 + ES < NE) ? e0 + ES : NE;
    for (int e = e0 + threadIdx.x; e < e1; e += 256) {
        int key = dst[e];
        int k = key - lo;
        if (k >= 0 && k < CH3) {
            int sh = (k & 3) << 3;
            unsigned old = atomicAdd(&cur[k >> 2], 1u << sh);
            int my = (int)((old >> sh) & 0xffu);
            int pos = offs[key] + my;
            sortedSrc[pos] = srcT[e];
        }
    }
}

// ---------------------------------------------------------------- FUSED layer-0: histogram + GEMM (K=96)
// Phase 1: threads 0-127 build per-node type-rel histograms (LDS cnt) and write
// A0 fragments into LDS.  Phase 2: MFMA GEMM from LDS.  No A0 global round-trip.
// A0L layout: [C=ks*4+quad (12)][tile(8)][l16(16)] 16B units.

__global__ __launch_bounds__(256) void gemm0_fused(const int* __restrict__ sortedSrc,
                                                   const int* __restrict__ offs,
                                                   const int* __restrict__ ntype,
                                                   const unsigned short* __restrict__ B0f,
                                                   const float* __restrict__ bias,
                                                   unsigned short* __restrict__ Cb,
                                                   float* __restrict__ bnSums, int M) {
    __shared__ unsigned short A0L[12 * 128 * 8];   // 24.6 KB
    __shared__ unsigned cnt[128][13];              // 6.7 KB
    __shared__ float sred[2][4][128];              // 4 KB
    const int tid = threadIdx.x;

    if (tid < 128) {
        const int n = blockIdx.x * 128 + tid;
        const int tile = tid >> 4, l16 = tid & 15;
        if (n < M) {
            #pragma unroll
            for (int t = 0; t < 13; ++t) cnt[tid][t] = 0;
            const int o0 = offs[n], o1 = offs[n + 1];
            unsigned relc = 0;
            for (int i = o0; i < o1; ++i) {
                int v = sortedSrc[i];
                int ty = (v >> 17) & 15, r = v >> 21;
                cnt[tid][ty] += 1u << (r << 3);
                relc += 1u << (r << 3);
            }
            float inv[4];
            #pragma unroll
            for (int r = 0; r < 4; ++r) {
                unsigned c = (relc >> (r << 3)) & 0xffu;
                inv[r] = 1.0f / (float)(c > 0 ? c : 1);
            }
            const int myty = ntype[n];
            #pragma unroll
            for (int ks = 0; ks < 3; ++ks) {
                #pragma unroll
                for (int quad = 0; quad < 4; ++quad) {
                    unsigned short vals[8];
                    #pragma unroll
                    for (int j = 0; j < 8; ++j) {
                        int p = ks * 32 + quad * 8 + j;
                        float v;
                        if (p < 32) v = (p == myty) ? 1.0f : 0.0f;
                        else {
                            int r = (p - 32) >> 4, tt = (p - 32) & 15;
                            v = (tt < 13) ? (float)((cnt[tid][tt] >> (r << 3)) & 0xffu) * inv[r] : 0.0f;
                        }
                        vals[j] = f2bf(v);
                    }
                    const int C = ks * 4 + quad;
                    *(uint4*)(A0L + (C * 128 + tile * 16 + l16) * 8) = *(uint4*)vals;
                }
            }
        } else {
            uint4 z; z.x = 0; z.y = 0; z.z = 0; z.w = 0;
            #pragma unroll
            for (int C = 0; C < 12; ++C)
                *(uint4*)(A0L + (C * 128 + tile * 16 + l16) * 8) = z;
        }
    }
    __syncthreads();

    // ---- GEMM phase
    const int wv = tid >> 6, lane = tid & 63;
    const int l16 = lane & 15, quad = lane >> 4;
    const int rowbase = blockIdx.x * 128 + wv * 32;
    const int tileL0 = wv * 2, tileL1 = wv * 2 + 1;

    float4v acc[2][8];
    #pragma unroll
    for (int t = 0; t < 8; ++t) {
        float bv = bias[t * 16 + l16];
        float4v av = {bv, bv, bv, bv};
        acc[0][t] = av; acc[1][t] = av;
    }

    const unsigned short* bl = B0f + lane * 8;
    #pragma unroll
    for (int ks = 0; ks < 3; ++ks) {
        const int C = ks * 4 + quad;
        short8 af0 = *(const short8*)(A0L + (C * 128 + tileL0 * 16 + l16) * 8);
        short8 af1 = *(const short8*)(A0L + (C * 128 + tileL1 * 16 + l16) * 8);
        const unsigned short* bp = bl + ((ks * 8) << 9);
        #pragma unroll
        for (int t = 0; t < 8; ++t) {
            short8 bf = *(const short8*)(bp + (t << 9));
            acc[0][t] = __builtin_amdgcn_mfma_f32_16x16x32_bf16(af0, bf, acc[0][t], 0, 0, 0);
            acc[1][t] = __builtin_amdgcn_mfma_f32_16x16x32_bf16(af1, bf, acc[1][t], 0, 0, 0);
        }
    }

    #pragma unroll
    for (int h = 0; h < 2; ++h) {
        #pragma unroll
        for (int rg = 0; rg < 4; ++rg) {
            int rr = rowbase + h * 16 + quad * 4 + rg;
            if (rr < M) {
                unsigned short v[8];
                #pragma unroll
                for (int t = 0; t < 8; ++t) v[t] = f2bf(acc[h][t][rg]);
                *(uint4*)(Cb + (size_t)rr * 128 + l16 * 8) = *(uint4*)v;
            }
        }
    }
    float s[8], q[8];
    #pragma unroll
    for (int t = 0; t < 8; ++t) {
        s[t] = 0.f; q[t] = 0.f;
        #pragma unroll
        for (int h = 0; h < 2; ++h) {
            #pragma unroll
            for (int rg = 0; rg < 4; ++rg) {
                int rr = rowbase + h * 16 + quad * 4 + rg;
                if (rr < M) { float v = acc[h][t][rg]; s[t] += v; q[t] += v * v; }
            }
        }
    }
    #pragma unroll
    for (int t = 0; t < 8; ++t) {
        s[t] += __shfl_down(s[t], 32, 64); q[t] += __shfl_down(q[t], 32, 64);
        s[t] += __shfl_down(s[t], 16, 64); q[t] += __shfl_down(q[t], 16, 64);
    }
    if (lane < 16) {
        #pragma unroll
        for (int t = 0; t < 8; ++t) {
            sred[0][wv][t * 16 + l16] = s[t];
            sred[1][wv][t * 16 + l16] = q[t];
        }
    }
    __syncthreads();
    if (tid < 128) {
        float S = sred[0][0][tid] + sred[0][1][tid] + sred[0][2][tid] + sred[0][3][tid];
        float Q = sred[1][0][tid] + sred[1][1][tid] + sred[1][2][tid] + sred[1][3][tid];
        float* bnS = bnSums + ((blockIdx.x & 7) << 8);
        unsafeAtomicAdd(bnS + tid, S);
        unsafeAtomicAdd(bnS + 128 + tid, Q);
    }
}

// ---------------------------------------------------------------- FUSED layer-1: gather + GEMM (unchanged, pinned)

__global__ __launch_bounds__(256) void gather_gemm1(const unsigned short* __restrict__ hbf,
                                                    const int* __restrict__ sortedSrc,
                                                    const int* __restrict__ offs,
                                                    const unsigned short* __restrict__ Bf,
                                                    const float* __restrict__ bias,
                                                    unsigned short* __restrict__ Cb,
                                                    float* __restrict__ bnSums) {
    __shared__ unsigned short rootL[2048];   // 4KB  (16B-unit swizzled)
    __shared__ unsigned short aggL[8192];    // 16KB (4 rel blocks, swizzled)
    const int tid = threadIdx.x;
    const int tile = blockIdx.x;
    {
        const int l16g = tid >> 4;
        const int cidx = tid & 15;
        const int c8 = cidx << 3;
        const int n = tile * 16 + l16g;                  // NN = 6250*16 exact
        const int pu = cidx * 16 + (l16g ^ cidx);        // swizzled unit
        uint4 ru = *(const uint4*)(hbf + (size_t)n * 128 + c8);
        *(uint4*)(rootL + pu * 8) = ru;

        const unsigned short* hb = hbf + c8;
        const int o0 = offs[n], o1 = offs[n + 1];

        float a0[8], a1[8], a2[8], a3[8];
        #pragma unroll
        for (int j = 0; j < 8; ++j) { a0[j] = 0.f; a1[j] = 0.f; a2[j] = 0.f; a3[j] = 0.f; }
        float c0 = 0.f, c1 = 0.f, c2 = 0.f, c3 = 0.f;

        auto body = [&](int v, uint4 u) {
            int r = v >> 21;
            float f[8];
            f[0] = __uint_as_float(u.x << 16); f[1] = __uint_as_float(u.x & 0xffff0000u);
            f[2] = __uint_as_float(u.y << 16); f[3] = __uint_as_float(u.y & 0xffff0000u);
            f[4] = __uint_as_float(u.z << 16); f[5] = __uint_as_float(u.z & 0xffff0000u);
            f[6] = __uint_as_float(u.w << 16); f[7] = __uint_as_float(u.w & 0xffff0000u);
            float m0 = (r == 0) ? 1.f : 0.f, m1 = (r == 1) ? 1.f : 0.f;
            float m2 = (r == 2) ? 1.f : 0.f, m3 = (r == 3) ? 1.f : 0.f;
            c0 += m0; c1 += m1; c2 += m2; c3 += m3;
            #pragma unroll
            for (int j = 0; j < 8; ++j) {
                a0[j] = fmaf(m0, f[j], a0[j]);
                a1[j] = fmaf(m1, f[j], a1[j]);
                a2[j] = fmaf(m2, f[j], a2[j]);
                a3[j] = fmaf(m3, f[j], a3[j]);
            }
        };

        int i = o0;
        for (; i + 4 <= o1; i += 4) {
            int v0 = sortedSrc[i], v1 = sortedSrc[i + 1];
            int v2 = sortedSrc[i + 2], v3 = sortedSrc[i + 3];
            uint4 u0 = *(const uint4*)(hb + (size_t)(v0 & 0x1ffff) * 128);
            uint4 u1 = *(const uint4*)(hb + (size_t)(v1 & 0x1ffff) * 128);
            uint4 u2 = *(const uint4*)(hb + (size_t)(v2 & 0x1ffff) * 128);
            uint4 u3 = *(const uint4*)(hb + (size_t)(v3 & 0x1ffff) * 128);
            body(v0, u0); body(v1, u1); body(v2, u2); body(v3, u3);
        }
        if (i + 2 <= o1) {
            int v0 = sortedSrc[i], v1 = sortedSrc[i + 1];
            uint4 u0 = *(const uint4*)(hb + (size_t)(v0 & 0x1ffff) * 128);
            uint4 u1 = *(const uint4*)(hb + (size_t)(v1 & 0x1ffff) * 128);
            body(v0, u0); body(v1, u1);
            i += 2;
        }
        if (i < o1) {
            int v0 = sortedSrc[i];
            uint4 u0 = *(const uint4*)(hb + (size_t)(v0 & 0x1ffff) * 128);
            body(v0, u0);
        }

        const float i0 = 1.f / fmaxf(c0, 1.f), i1 = 1.f / fmaxf(c1, 1.f);
        const float i2 = 1.f / fmaxf(c2, 1.f), i3 = 1.f / fmaxf(c3, 1.f);
        unsigned short* bp = aggL + pu * 8;
        auto pack = [&](float* a, float inv, unsigned short* dp) {
            unsigned short v[8];
            #pragma unroll
            for (int j = 0; j < 8; ++j) v[j] = f2bf(a[j] * inv);
            *(uint4*)dp = *(uint4*)v;
        };
        pack(a0, i0, bp);
        pack(a1, i1, bp + 2048);
        pack(a2, i2, bp + 4096);
        pack(a3, i3, bp + 6144);
    }
    __syncthreads();

    // ---- GEMM phase: wave wv handles output cols t0=2wv, t0+1
    const int wv = tid >> 6, lane = tid & 63;
    const int l16 = lane & 15, quad = lane >> 4;
    const int t0 = wv << 1;
    float4v acc0, acc1;
    {
        float b0v = bias[t0 * 16 + l16];
        float b1v = bias[(t0 + 1) * 16 + l16];
        float4v a0v = {b0v, b0v, b0v, b0v};
        float4v a1v = {b1v, b1v, b1v, b1v};
        acc0 = a0v; acc1 = a1v;
    }
    const unsigned short* bl = Bf + lane * 8;
    #pragma unroll
    for (int kc = 0; kc < 5; ++kc) {
        const unsigned short* Abase = (kc == 0) ? rootL : (aggL + (kc - 1) * 2048);
        #pragma unroll
        for (int ks = 0; ks < 4; ++ks) {
            const int C = ks * 4 + quad;
            const int p = C * 16 + (l16 ^ C);
            short8 af = *(const short8*)(Abase + p * 8);
            const unsigned short* bp = bl + (((kc * 4 + ks) * 8 + t0) << 9);
            short8 b0 = *(const short8*)(bp);
            short8 b1 = *(const short8*)(bp + 512);
            acc0 = __builtin_amdgcn_mfma_f32_16x16x32_bf16(af, b0, acc0, 0, 0, 0);
            acc1 = __builtin_amdgcn_mfma_f32_16x16x32_bf16(af, b1, acc1, 0, 0, 0);
        }
    }
    const int rowbase = tile * 16;
    #pragma unroll
    for (int rg = 0; rg < 4; ++rg) {
        int rr = rowbase + quad * 4 + rg;
        unsigned pk = (unsigned)f2bf(acc0[rg]) | ((unsigned)f2bf(acc1[rg]) << 16);
        *(unsigned*)(Cb + (size_t)rr * 128 + l16 * 8 + t0) = pk;
    }
    float s0 = 0.f, q0 = 0.f, s1 = 0.f, q1 = 0.f;
    #pragma unroll
    for (int rg = 0; rg < 4; ++rg) {
        float v0 = acc0[rg], v1 = acc1[rg];
        s0 += v0; q0 += v0 * v0; s1 += v1; q1 += v1 * v1;
    }
    s0 += __shfl_down(s0, 32, 64); q0 += __shfl_down(q0, 32, 64);
    s1 += __shfl_down(s1, 32, 64); q1 += __shfl_down(q1, 32, 64);
    s0 += __shfl_down(s0, 16, 64); q0 += __shfl_down(q0, 16, 64);
    s1 += __shfl_down(s1, 16, 64); q1 += __shfl_down(q1, 16, 64);
    if (lane < 16) {
        float* bnS = bnSums + ((tile & 7) << 8);
        unsafeAtomicAdd(bnS + t0 * 16 + l16, s0);
        unsafeAtomicAdd(bnS + 128 + t0 * 16 + l16, q0);
        unsafeAtomicAdd(bnS + (t0 + 1) * 16 + l16, s1);
        unsafeAtomicAdd(bnS + 128 + (t0 + 1) * 16 + l16, q1);
    }
}

// ---------------------------------------------------------------- BN finalize layer-0: fold -> fin, then re-zero bnSums

__global__ void bn_finalize0(float* __restrict__ bnSums, float* __restrict__ fin, int n) {
    const int c = threadIdx.x;   // 256
    if (c < 128) {
        float s = 0.f, q = 0.f;
        #pragma unroll
        for (int j = 0; j < 8; ++j) { s += bnSums[j * 256 + c]; q += bnSums[j * 256 + 128 + c]; }
        const float invn = 1.0f / (float)n;
        float mu = s * invn;
        float var = q * invn - mu * mu; if (var < 0.f) var = 0.f;
        fin[c] = mu;
        fin[128 + c] = rsqrtf(var + 1e-5f);
    }
    __syncthreads();
    for (int i = c; i < 2048; i += 256) bnSums[i] = 0.f;
}

// ---------------------------------------------------------------- BN finalize layer-1 (+ g0 zero)

__global__ void bn_finalize(const float* __restrict__ bnSums, float* __restrict__ fin,
                            float* __restrict__ g0zero, int n) {
    const int c = threadIdx.x;   // 128
    if (g0zero) g0zero[blockIdx.x * 128 + c] = 0.f;
    if (blockIdx.x != 0) return;
    float s = 0.f, q = 0.f;
    #pragma unroll
    for (int j = 0; j < 8; ++j) { s += bnSums[j * 256 + c]; q += bnSums[j * 256 + 128 + c]; }
    const float invn = 1.0f / (float)n;
    float mu = s * invn;
    float var = q * invn - mu * mu; if (var < 0.f) var = 0.f;
    fin[c] = mu;
    fin[128 + c] = rsqrtf(var + 1e-5f);
}

// ---------------------------------------------------------------- layer-0 BN/PReLU/L2norm -> hbf

__global__ __launch_bounds__(256) void bn_apply_kernel(const unsigned short* __restrict__ Cb,
                                unsigned short* __restrict__ hbf,
                                const float* __restrict__ fin,
                                const float* __restrict__ gamma, const float* __restrict__ beta,
                                const float* __restrict__ prelu_a, int layer) {
    const int tid = threadIdx.x;
    const int row = blockIdx.x * 16 + (tid >> 4);
    const int li = tid & 15;
    const int p8 = li << 3;
    const float a = prelu_a[layer];
    uint4 u = *(const uint4*)(Cb + (size_t)row * 128 + p8);
    float v[8];
    v[0] = __uint_as_float(u.x << 16); v[1] = __uint_as_float(u.x & 0xffff0000u);
    v[2] = __uint_as_float(u.y << 16); v[3] = __uint_as_float(u.y & 0xffff0000u);
    v[4] = __uint_as_float(u.z << 16); v[5] = __uint_as_float(u.z & 0xffff0000u);
    v[6] = __uint_as_float(u.w << 16); v[7] = __uint_as_float(u.w & 0xffff0000u);
    float t[8]; float ss = 0.f;
    #pragma unroll
    for (int j = 0; j < 8; ++j) {
        int cc = j * 16 + li;
        float tv = (v[j] - fin[cc]) * fin[128 + cc] * gamma[cc] + beta[cc];
        tv = (tv >= 0.f) ? tv : a * tv;
        t[j] = tv; ss += tv * tv;
    }
    ss += __shfl_xor(ss, 1, 64);
    ss += __shfl_xor(ss, 2, 64);
    ss += __shfl_xor(ss, 4, 64);
    ss += __shfl_xor(ss, 8, 64);
    const float scale = 1.0f / fmaxf(sqrtf(ss), 1e-12f);
    unsigned short o[8];
    #pragma unroll
    for (int j = 0; j < 8; ++j) o[j] = f2bf(t[j] * scale);
    *(uint4*)(hbf + (size_t)row * 128 + p8) = *(uint4*)o;
}

// ---------------------------------------------------------------- layer-1 BN/PReLU/L2norm + fused pooling

__global__ __launch_bounds__(256) void bn_apply_pool(const unsigned short* __restrict__ Cb,
                                const float* __restrict__ fin,
                                const float* __restrict__ gamma, const float* __restrict__ beta,
                                const float* __restrict__ prelu_a,
                                const int* __restrict__ batch,
                                float* __restrict__ g0) {
    __shared__ float P[16][128];
    __shared__ int gids[16];
    const int tid = threadIdx.x;
    const int r16 = tid >> 4;
    const int li = tid & 15;
    const int row = blockIdx.x * 16 + r16;
    const int p8 = li << 3;
    if (li == 0) gids[r16] = batch[row];
    const float a = prelu_a[1];
    uint4 u = *(const uint4*)(Cb + (size_t)row * 128 + p8);
    float v[8];
    v[0] = __uint_as_float(u.x << 16); v[1] = __uint_as_float(u.x & 0xffff0000u);
    v[2] = __uint_as_float(u.y << 16); v[3] = __uint_as_float(u.y & 0xffff0000u);
    v[4] = __uint_as_float(u.z << 16); v[5] = __uint_as_float(u.z & 0xffff0000u);
    v[6] = __uint_as_float(u.w << 16); v[7] = __uint_as_float(u.w & 0xffff0000u);
    float t[8]; float ss = 0.f;
    #pragma unroll
    for (int j = 0; j < 8; ++j) {
        int cc = j * 16 + li;
        float tv = (v[j] - fin[cc]) * fin[128 + cc] * gamma[cc] + beta[cc];
        tv = (tv >= 0.f) ? tv : a * tv;
        t[j] = tv; ss += tv * tv;
    }
    ss += __shfl_xor(ss, 1, 64);
    ss += __shfl_xor(ss, 2, 64);
    ss += __shfl_xor(ss, 4, 64);
    ss += __shfl_xor(ss, 8, 64);
    const float scale = 1.0f / fmaxf(sqrtf(ss), 1e-12f);
    #pragma unroll
    for (int j = 0; j < 8; ++j) P[r16][p8 + j] = t[j] * scale;
    __syncthreads();
    if (tid < 128) {
        int cur = gids[0];
        float run = 0.f;
        #pragma unroll
        for (int rr = 0; rr < 16; ++rr) {
            int g = gids[rr];
            if (g != cur) {
                unsafeAtomicAdd(&g0[(size_t)cur * 128 + tid], run);
                run = 0.f; cur = g;
            }
            run += P[rr][tid];
        }
        unsafeAtomicAdd(&g0[(size_t)cur * 128 + tid], run);
    }
}

// ---------------------------------------------------------------- MLP (fc1 applies 1/cnt)

__global__ void fc1_kernel(const float* __restrict__ g, const float* __restrict__ w,
                           const float* __restrict__ b, const int* __restrict__ batch,
                           float* __restrict__ o) {
    const int row = blockIdx.x;   // 512
    const int j = threadIdx.x;    // 256
    const int lo = lower_bound_dev(batch, NN, row);
    const int hi = lower_bound_dev(batch, NN, row + 1);
    const int c = hi - lo;
    const float invc = 1.0f / (float)(c > 0 ? c : 1);
    float acc = 0.f;
    #pragma unroll 8
    for (int k = 0; k < 128; ++k) {
        int lk = (k & 7) * 16 + (k >> 3);         // logical feature for mem pos k
        acc += g[row * 128 + k] * w[lk * 256 + j];
    }
    o[row * 256 + j] = fmaxf(acc * invc + b[j], 0.f);
}

__global__ void fc2_kernel(const float* __restrict__ g, const float* __restrict__ w,
                           const float* __restrict__ b, float* __restrict__ o) {
    const int row = blockIdx.x;   // 512
    const int j = threadIdx.x;    // 128
    float acc = b[j];
    #pragma unroll 8
    for (int k = 0; k < 256; ++k) acc += g[row * 256 + k] * w[k * 128 + j];
    o[row * 128 + j] = fmaxf(acc, 0.f);
}

__global__ void fco_kernel(const float* __restrict__ g, const float* __restrict__ w,
                           const float* __restrict__ b, float* __restrict__ o) {
    const int row = blockIdx.x * blockDim.x + threadIdx.x;
    if (row >= NG) return;
    float acc = b[0];
    #pragma unroll 8
    for (int k = 0; k < 128; ++k) acc += g[row * 128 + k] * w[k];
    o[row] = acc;
}

// ---------------------------------------------------------------- launcher

extern "C" void kernel_launch(void* const* d_in, const int* in_sizes, int n_in,
                              void* d_out, int out_size, void* d_ws, size_t ws_size,
                              hipStream_t stream) {
    const float* x      = (const float*)d_in[0];
    const int*   eidx   = (const int*)d_in[1];
    const int*   etype  = (const int*)d_in[2];
    const int*   batch  = (const int*)d_in[3];
    const float* emb    = (const float*)d_in[4];
    const float* Wrel   = (const float*)d_in[5];
    const float* Wroot  = (const float*)d_in[6];
    const float* cbias  = (const float*)d_in[7];
    const float* gamma  = (const float*)d_in[8];
    const float* beta   = (const float*)d_in[9];
    const float* prelua = (const float*)d_in[10];
    const float* fc1w   = (const float*)d_in[11];
    const float* fc1b   = (const float*)d_in[12];
    const float* fc2w   = (const float*)d_in[13];
    const float* fc2b   = (const float*)d_in[14];
    const float* outw   = (const float*)d_in[15];
    const float* outb   = (const float*)d_in[16];
    float* out = (float*)d_out;

    const int* src = eidx;
    const int* dst = eidx + NE;

    // workspace carve-up (aligned 256B)
    char* p = (char*)d_ws;
    auto alloc = [&](size_t bytes) { char* r = p; p += (bytes + 255) & ~(size_t)255; return r; };
    unsigned short* hbf   = (unsigned short*)alloc((size_t)NN * 128 * 2);  // 25.6 MB
    unsigned short* Cb    = (unsigned short*)alloc((size_t)NN * 128 * 2);  // 25.6 MB
    unsigned* partials = (unsigned*)alloc((size_t)NCH * BPC * CHW * 4);    // 16.8 MB
    int*   sortedSrc = (int*)alloc((size_t)NE * 4);                        // 6.4 MB
    int*   srcT      = (int*)alloc((size_t)NE * 4);                        // 6.4 MB
    int*   offs      = (int*)alloc((size_t)(NN + 1) * 4);
    int*   bsums     = (int*)alloc(1024);
    int*   ntype     = (int*)alloc((size_t)NN * 4);
    unsigned short* Bf1 = (unsigned short*)alloc((size_t)81920 * 2);
    unsigned short* B0f = (unsigned short*)alloc((size_t)12288 * 2);
    float* bnSums  = (float*)alloc(2048 * 4);
    float* bnFin   = (float*)alloc(256 * 4);
    float* g0      = (float*)alloc((size_t)NG * 128 * 4);
    float* g1      = (float*)alloc((size_t)NG * 256 * 4);
    float* g2      = (float*)alloc((size_t)NG * 128 * 4);

    const int NBLK = (NN + 1023) / 1024;   // 98

    // ---- node types, weight fragments (+ bnSums zero)
    node_type_kernel<<<(NN + 255) / 256, 256, 0, stream>>>(x, ntype, NN);
    build_weights<<<368, 256, 0, stream>>>(emb, Wroot, Wrel, Bf1, B0f, bnSums);

    // ---- CSR build over dst (2 chunk passes; chunk-0 also packs srcT)
    hist_kernel<<<dim3(BPC, NCH), 256, 0, stream>>>(dst, src, etype, ntype, srcT, partials);
    hist_reduce<<<dim3(CHW / 256, NCH), 256, 0, stream>>>(partials, offs);
    scan1<<<NBLK, 256, 0, stream>>>(offs, offs, bsums, NN);
    scan2<<<1, 64, 0, stream>>>(bsums, offs, NBLK, NN);
    scan3<<<NBLK, 256, 0, stream>>>(offs, bsums, NN);
    place_kernel<<<dim3(BPC, NCH), 256, 0, stream>>>(dst, srcT, offs, partials, sortedSrc);

    // ---- layer 0: fused histogram + GEMM (A0 never leaves LDS)
    gemm0_fused<<<(NN + 127) / 128, 256, 0, stream>>>(sortedSrc, offs, ntype, B0f,
                                                      cbias, Cb, bnSums, NN);
    bn_finalize0<<<1, 256, 0, stream>>>(bnSums, bnFin, NN);
    bn_apply_kernel<<<NN / 16, 256, 0, stream>>>(Cb, hbf, bnFin, gamma, beta, prelua, 0);

    // ---- layer 1: fused gather + GEMM (pinned), then BN + fused pooling
    gather_gemm1<<<NN / 16, 256, 0, stream>>>(hbf, sortedSrc, offs, Bf1, cbias + 128, Cb, bnSums);
    bn_finalize<<<512, 128, 0, stream>>>(bnSums, bnFin, g0, NN);
    bn_apply_pool<<<NN / 16, 256, 0, stream>>>(Cb, bnFin, gamma + 128, beta + 128,
                                               prelua, batch, g0);

    // ---- MLP (fc1 folds 1/cnt)
    fc1_kernel<<<NG, 256, 0, stream>>>(g0, fc1w, fc1b, batch, g1);
    fc2_kernel<<<NG, 128, 0, stream>>>(g1, fc2w, fc2b, g2);
    fco_kernel<<<2, 256, 0, stream>>>(g2, outw, outb, out);
}